// Round 12
// baseline (303.494 us; speedup 1.0000x reference)
//
#include <hip/hip_runtime.h>
#include <math.h>

namespace {
constexpr int BATCH = 32;
constexpr int NANCH = 15130;
constexpr int NCLS  = 81;
constexpr int C1    = 80;          // foreground classes
constexpr int MAXO  = 200;
constexpr int APB   = 256;         // anchors per K1 block (= threads)
constexpr int NBLKA = (NANCH + APB - 1) / APB;   // 60
constexpr int CAPK2 = 512;         // K2 cand capacity (live path uses <=256)
constexpr int CAP   = 1024;        // K3 cand capacity
constexpr int CAPB  = 768;         // global bucket capacity (mean 434, sigma 20.5)
constexpr int NWORD = 4;           // 256 bits >= 200 for NMS bitmask
constexpr int NBIN  = 2048;        // histogram bins for K3 select
constexpr int NBINK2 = 768;        // K2 bins (shift 16); max used bin 641
constexpr unsigned BINBASE = 0x3D000000u;  // 0.03125f — below any score > 0.05
constexpr int IMGCAP = C1 * MAXO;  // 16000 — worst-case kept per image
}

#define SCORE_TH 0.05f
#define IOU_TH   0.5f

typedef unsigned long long u64;

__device__ __forceinline__ u64 shflx64(u64 v, int mask) {
    int lo = __shfl_xor((int)(unsigned)(v & 0xffffffffull), mask, 64);
    int hi = __shfl_xor((int)(unsigned)(v >> 32), mask, 64);
    return ((u64)(unsigned)hi << 32) | (unsigned)lo;
}

// Descending bitonic sort of P (power of 2) u64 keys in LDS (fallback path).
// Key = (float_bits(score) << 32) | (0xFFFFFFFF - index)
// => order: score desc, then index asc (matches jax.lax.top_k stability).
__device__ __forceinline__ void bitonic_desc(u64* keys, int P,
                                             int tid, int nthr) {
    for (int k = 2; k <= P; k <<= 1) {
        for (int j = k >> 1; j > 0; j >>= 1) {
            for (int i = tid; i < P; i += nthr) {
                int ixj = i ^ j;
                if (ixj > i) {
                    u64 a = keys[i], c = keys[ixj];
                    bool up = ((i & k) == 0);
                    if (up ? (a < c) : (a > c)) { keys[i] = c; keys[ixj] = a; }
                }
            }
            __syncthreads();
        }
    }
}

// Register bitonic sort of 256 keys (one per thread). j<64 phases via
// cross-lane shuffles; j in {64,128} via LDS round-trip. Same network.
__device__ __forceinline__ u64 regsort256(u64 key, u64* lds, int tid) {
    for (int k = 2; k <= 256; k <<= 1) {
        for (int j = k >> 1; j > 0; j >>= 1) {
            u64 pv;
            if (j < 64) {
                pv = shflx64(key, j);
            } else {
                lds[tid] = key;
                __syncthreads();
                pv = lds[tid ^ j];
            }
            bool up = ((tid & k) == 0);
            bool lt = ((tid & j) == 0);
            u64 mx = (key > pv) ? key : pv;
            u64 mn = (key > pv) ? pv : key;
            key = (up == lt) ? mx : mn;
            if (j >= 64) __syncthreads();
        }
    }
    return key;
}

// Kernel 1: one thread per anchor, 81 logits in registers. Exact reference
// op order throughout.
__global__ __launch_bounds__(256, 3) void ssd_decode_stats(
    const float* __restrict__ ploc, const float* __restrict__ plabel,
    const float* __restrict__ dboxes,
    float* __restrict__ ltrb, float* __restrict__ rowmax,
    float* __restrict__ rowsum,
    int* __restrict__ cntg, u64* __restrict__ bucket) {
#pragma clang fp contract(off)
    __shared__ int lcnt[C1], lbase[C1], lrank[C1];

    const int tid = threadIdx.x;
    const int b   = blockIdx.x / NBLKA;
    const int n0  = (blockIdx.x % NBLKA) * APB;
    const int n   = n0 + tid;
    const bool act = (n < NANCH);

    if (tid < C1) lcnt[tid] = 0;

    float x[NCLS];
    if (act) {
        const float* pl = ploc + (size_t)b * 4 * NANCH + n;
        float px = pl[0], py = pl[NANCH], pw = pl[2 * NANCH],
              ph = pl[3 * NANCH];
        float4 db = reinterpret_cast<const float4*>(dboxes)[n];
        float cx = px * 0.1f * db.z + db.x;
        float cy = py * 0.1f * db.w + db.y;
        float w  = expf(pw * 0.2f) * db.z;
        float h  = expf(ph * 0.2f) * db.w;
        float4 o;
        o.x = cx - 0.5f * w; o.y = cy - 0.5f * h;
        o.z = cx + 0.5f * w; o.w = cy + 0.5f * h;
        reinterpret_cast<float4*>(ltrb)[(size_t)b * NANCH + n] = o;

        const float* pb = plabel + (size_t)b * NCLS * NANCH + n;
#pragma unroll
        for (int c = 0; c < NCLS; ++c) x[c] = pb[(size_t)c * NANCH];

        float m = -INFINITY;
#pragma unroll
        for (int c = 0; c < NCLS; ++c) m = fmaxf(m, x[c]);
#pragma unroll
        for (int c = 0; c < NCLS; ++c) x[c] = expf(x[c] - m);
        float s = 0.f;
#pragma unroll
        for (int c = 0; c < NCLS; ++c) s += x[c];   // serial, reference order
        rowmax[(size_t)b * NANCH + n] = m;
        rowsum[(size_t)b * NANCH + n] = s;

#pragma unroll
        for (int c = 1; c < NCLS; ++c) {
            x[c] = x[c] / s;   // exact IEEE div = reference value
            if (x[c] > SCORE_TH) atomicAdd(&lcnt[c - 1], 1);
        }
    }
    __syncthreads();

    if (tid < C1) {
        int cn = lcnt[tid];
        lbase[tid] = (cn > 0) ? atomicAdd(&cntg[b * C1 + tid], cn) : 0;
        lrank[tid] = 0;
    }
    __syncthreads();

    if (act) {
#pragma unroll
        for (int c = 1; c < NCLS; ++c) {
            if (x[c] > SCORE_TH) {
                int r = atomicAdd(&lrank[c - 1], 1);
                int pos = lbase[c - 1] + r;
                if (pos < CAPB)
                    bucket[(size_t)(b * C1 + (c - 1)) * CAPB + pos] =
                        ((u64)__float_as_uint(x[c]) << 32)
                        | (u64)(0xFFFFFFFFu - (unsigned)n);
            }
        }
    }
}

// Kernel 2: per (b, class): histogram-select ~top-200, register bitonic sort,
// LAZY NMS: suppression rows computed on demand only for surviving i
// (~40 rows instead of 200). Exact reference greedy recurrence.
__global__ __launch_bounds__(256, 8) void ssd_class_nms(
    const float* __restrict__ plabel, const float* __restrict__ rowmax,
    const float* __restrict__ rowsum, const float* __restrict__ ltrb,
    const int* __restrict__ cntg, const u64* __restrict__ bucket,
    float* __restrict__ pcVals, float* __restrict__ pcBoxes,
    int* __restrict__ imgcnt, u64* __restrict__ imglist) {
    __shared__ u64 cand[CAPK2];               // 4 KB
    __shared__ unsigned int hist[NBINK2];     // 3 KB (reused as fill scratch)
    __shared__ float4 box4[MAXO];             // 3.2 KB
    __shared__ float areas[MAXO], vs[MAXO];   // 1.6 KB
    __shared__ u64 keepw[NWORD], vmaskS[NWORD], supRow[NWORD];
    __shared__ int wtot[4];
    __shared__ int cnt, fillcnt, cutbin, kcnt, kbase, curI;

    const int tid  = threadIdx.x;
    const int lane = tid & 63;
    const int wv   = tid >> 6;
    const int b    = blockIdx.x / C1;
    const int cls  = blockIdx.x % C1 + 1;   // skip background
    const int bc   = b * C1 + (cls - 1);

    for (int i = tid; i < NBINK2; i += 256) hist[i] = 0u;
    if (tid == 0) { cnt = 0; fillcnt = 0; cutbin = 1; kcnt = 0; }
    __syncthreads();

    const float* pl = plabel + ((size_t)b * NCLS + cls) * NANCH;
    const float* rm = rowmax + (size_t)b * NANCH;
    const float* rs = rowsum + (size_t)b * NANCH;
    const u64* bkt = bucket + (size_t)bc * CAPB;

    const int gcount = cntg[bc];
    const bool ovf = (gcount > CAPB);   // uniform; dead in practice
    int gathered;

    if (!ovf) {
        const int count = gcount;
        // Pass 1: histogram (bin = ((bits-BINBASE)>>16)+1, monotone in value).
        for (int i = tid; i < count; i += 256) {
            unsigned bits = (unsigned)(bkt[i] >> 32);
            unsigned bin = ((bits - BINBASE) >> 16) + 1u;
            if (bin > NBINK2 - 1) bin = NBINK2 - 1;
            atomicAdd(&hist[bin], 1u);
        }
        __syncthreads();

        // Per-thread group sum (3 bins), wave suffix-scan, cross-wave combine.
        const int base = tid * 3;
        int loc = (int)hist[base] + (int)hist[base + 1] + (int)hist[base + 2];
        int sfx = loc;
        for (int off = 1; off < 64; off <<= 1) {
            int t = __shfl_down(sfx, off, 64);
            if (lane + off < 64) sfx += t;
        }
        if (lane == 0) wtot[wv] = sfx;
        __syncthreads();
        int crossSuf = 0;
        for (int w2 = wv + 1; w2 < 4; ++w2) crossSuf += wtot[w2];
        const int nztot = wtot[0] + wtot[1] + wtot[2] + wtot[3];
        {
            int S = (sfx - loc) + crossSuf;
            for (int k = 2; k >= 0; --k) {
                int binv = (int)hist[base + k];
                int Sk = S + binv;
                int bin = base + k;
                if (bin >= 1 && Sk >= MAXO && S < MAXO) cutbin = bin;
                S = Sk;
            }
        }
        __syncthreads();
        const int B = (nztot >= MAXO) ? cutbin : 1;

        // Pass 2: gather keys with bin >= B (top-200 subset; ~205 items).
        for (int i = tid; i < count; i += 256) {
            u64 k = bkt[i];
            unsigned bits = (unsigned)(k >> 32);
            unsigned bin = ((bits - BINBASE) >> 16) + 1u;
            if (bin > NBINK2 - 1) bin = NBINK2 - 1;
            if ((int)bin >= B) {
                int pos = atomicAdd(&cnt, 1);
                if (pos < CAPK2) cand[pos] = k;
            }
        }
        __syncthreads();
        gathered = min(cnt, CAPK2);
    } else {
        // Overflow fallback (dead): full rescan, no select.
        for (int n = tid; n < NANCH; n += 256) {
            float p = expf(pl[n] - rm[n]) / rs[n];
            if (p > SCORE_TH) {
                int pos = atomicAdd(&cnt, 1);
                if (pos < CAPK2)
                    cand[pos] = ((u64)__float_as_uint(p) << 32)
                              | (u64)(0xFFFFFFFFu - (unsigned)n);
            }
        }
        __syncthreads();
        gathered = min(cnt, CAPK2);
    }

    u64 key;
    if (gathered <= 256) {
        key = (tid < gathered) ? cand[tid] : 0ull;
        key = regsort256(key, cand, tid);
    } else {
        for (int i = gathered + tid; i < CAPK2; i += 256) cand[i] = 0ull;
        __syncthreads();
        bitonic_desc(cand, CAPK2, tid, 256);
        key = cand[tid];
    }

    // <200 positives: fill with smallest anchor idx (top_k zero tie-break). Dead.
    if (gathered < MAXO) {
        int* scanb = (int*)hist;
        cand[tid] = key;
        __syncthreads();
        const int need = MAXO - gathered;
        for (int base2 = 0; base2 < NANCH; base2 += 256) {
            if (fillcnt >= need) break;
            int n = base2 + tid;
            int flag = 0;
            if (n < NANCH) {
                float p = expf(pl[n] - rm[n]) / rs[n];
                flag = (p <= SCORE_TH) ? 1 : 0;
            }
            scanb[tid] = flag;
            __syncthreads();
            for (int off = 1; off < 256; off <<= 1) {
                int v  = scanb[tid];
                int vp = (tid >= off) ? scanb[tid - off] : 0;
                __syncthreads();
                scanb[tid] = v + vp;
                __syncthreads();
            }
            int excl = scanb[tid] - flag;
            if (flag && (fillcnt + excl) < need)
                cand[gathered + fillcnt + excl] =
                    (u64)(0xFFFFFFFFu - (unsigned)n);
            __syncthreads();
            if (tid == 0) fillcnt += scanb[255];
            __syncthreads();
        }
        __syncthreads();
        key = cand[tid];
    }

    // Gather top-200 boxes/scores into LDS + per-thread registers.
    float4 bjr = make_float4(0.f, 0.f, 0.f, 0.f);
    float ajr = 0.f, vsr = 0.f;
    if (tid < MAXO) {
#pragma clang fp contract(off)
        vsr = __uint_as_float((unsigned)(key >> 32));
        unsigned n = 0xFFFFFFFFu - (unsigned)(key & 0xFFFFFFFFull);
        bjr = reinterpret_cast<const float4*>(ltrb)[(size_t)b * NANCH + n];
        ajr = (bjr.z - bjr.x) * (bjr.w - bjr.y);
        box4[tid] = bjr;
        areas[tid] = ajr;
        vs[tid] = vsr;
    }
    {
        bool pred = (tid < MAXO) && (vsr > 0.f);
        u64 bal = __ballot(pred);
        if (lane == 0) vmaskS[wv] = bal;
    }
    if (tid == 0) {
        keepw[0] = ~0ull; keepw[1] = ~0ull; keepw[2] = ~0ull; keepw[3] = ~0ull;
    }
    __syncthreads();

    // Lazy greedy NMS: process only surviving rows, in increasing order —
    // exactly the reference fori_loop (skipped i have keep[i]&&vals[i]>0
    // false and contribute nothing there either).
    if (tid == 0) {
        int ni = -1;
        u64 c0 = keepw[0] & vmaskS[0];
        if (c0) ni = __builtin_ctzll(c0);
        else {
            u64 c1 = keepw[1] & vmaskS[1];
            if (c1) ni = 64 + __builtin_ctzll(c1);
            else {
                u64 c2 = keepw[2] & vmaskS[2];
                if (c2) ni = 128 + __builtin_ctzll(c2);
                else {
                    u64 c3 = keepw[3] & vmaskS[3];
                    if (c3) ni = 192 + __builtin_ctzll(c3);
                }
            }
        }
        curI = ni;
    }
    __syncthreads();

    while (true) {
        const int i = curI;   // uniform (LDS, barrier-ordered)
        if (i < 0) break;
        bool sup = false;
        if (tid > i && tid < MAXO) {
#pragma clang fp contract(off)
            float4 bi = box4[i];      // broadcast
            float ai = areas[i];      // broadcast
            float l = fmaxf(bi.x, bjr.x);
            float t = fmaxf(bi.y, bjr.y);
            float r = fminf(bi.z, bjr.z);
            float d = fminf(bi.w, bjr.w);
            float ww = fmaxf(r - l, 0.f);
            float hh = fmaxf(d - t, 0.f);
            float inter = ww * hh;
            float denom = ai + ajr - inter + 1e-12f;
            sup = ((inter / denom) >= IOU_TH);   // exact IEEE div
        }
        u64 bal = __ballot(sup);
        if (lane == 0) supRow[wv] = bal;
        __syncthreads();
        if (tid == 0) {
            keepw[0] &= ~supRow[0];
            keepw[1] &= ~supRow[1];
            keepw[2] &= ~supRow[2];
            keepw[3] &= ~supRow[3];
            int w = i >> 6, bit = i & 63;
            u64 above = (bit == 63) ? 0ull : (~0ull << (bit + 1));
            int ni = -1;
            u64 cur = keepw[w] & vmaskS[w] & above;
            while (true) {
                if (cur) { ni = w * 64 + __builtin_ctzll(cur); break; }
                if (++w >= 4) break;
                cur = keepw[w] & vmaskS[w];
            }
            curI = ni;
        }
        __syncthreads();
    }

    bool kp = false;
    if (tid < MAXO) {
        kp = (keepw[tid >> 6] >> (tid & 63)) & 1ull;
        pcVals[(size_t)bc * MAXO + tid] = (kp && vsr > 0.f) ? vsr : 0.f;
        reinterpret_cast<float4*>(pcBoxes + (size_t)bc * MAXO * 4)[tid] = bjr;
    }

    // Compact kept keys into the per-image list (set-equal to dense nonzeros).
    bool keep_me = (tid < MAXO) && kp && (vsr > 0.f);
    int r = -1;
    if (keep_me) r = atomicAdd(&kcnt, 1);
    __syncthreads();
    if (tid == 0) kbase = (kcnt > 0) ? atomicAdd(&imgcnt[b], kcnt) : 0;
    __syncthreads();
    if (keep_me) {
        unsigned g = (unsigned)((cls - 1) * MAXO + tid);
        imglist[(size_t)b * IMGCAP + kbase + r] =
            ((u64)__float_as_uint(vsr) << 32) | (u64)(0xFFFFFFFFu - g);
    }
}

// Kernel 3: per image, exact top-200. Live path reads the compact kept list
// (~2-4k entries); dense fallback (NZ<200) kept verbatim.
__global__ __launch_bounds__(256) void ssd_final_topk(
    const float* __restrict__ pcVals, const float* __restrict__ pcBoxes,
    const int* __restrict__ imgcnt, const u64* __restrict__ imglist,
    float* __restrict__ out) {
    __shared__ unsigned int hist[NBIN];
    __shared__ u64 cand[CAP];
    __shared__ int wtot[4];
    __shared__ int cnt, cutbin, nztot;

    const int tid  = threadIdx.x;
    const int lane = tid & 63;
    const int wv   = tid >> 6;
    const int b    = blockIdx.x;
    const int TOT  = C1 * MAXO;   // 16000
    const float* pv = pcVals + (size_t)b * TOT;
    const int NZ   = imgcnt[b];

    for (int i = tid; i < NBIN; i += 256) hist[i] = 0u;
    if (tid == 0) { cnt = 0; cutbin = 1; }
    __syncthreads();

    int count;
    if (NZ >= MAXO) {
        const u64* lst = imglist + (size_t)b * IMGCAP;
        for (int i = tid; i < NZ; i += 256) {
            unsigned bits = (unsigned)(lst[i] >> 32);
            unsigned bin = ((bits - BINBASE) >> 15) + 1u;
            if (bin > NBIN - 1) bin = NBIN - 1;
            atomicAdd(&hist[bin], 1u);
        }
        __syncthreads();

        const int base = tid * 8;
        int loc = 0;
        for (int k = 0; k < 8; ++k) loc += (int)hist[base + k];
        int sfx = loc;
        for (int off = 1; off < 64; off <<= 1) {
            int t = __shfl_down(sfx, off, 64);
            if (lane + off < 64) sfx += t;
        }
        if (lane == 0) wtot[wv] = sfx;
        __syncthreads();
        int crossSuf = 0;
        for (int w2 = wv + 1; w2 < 4; ++w2) crossSuf += wtot[w2];
        {
            int S = (sfx - loc) + crossSuf;
            for (int k = 7; k >= 0; --k) {
                int binv = (int)hist[base + k];
                int Sk = S + binv;
                int bin = base + k;
                if (bin >= 1 && Sk >= MAXO && S < MAXO) cutbin = bin;
                S = Sk;
            }
        }
        __syncthreads();
        const int B = cutbin;

        for (int i = tid; i < NZ; i += 256) {
            u64 k = lst[i];
            unsigned bits = (unsigned)(k >> 32);
            unsigned bin = ((bits - BINBASE) >> 15) + 1u;
            if (bin > NBIN - 1) bin = NBIN - 1;
            if ((int)bin >= B) {
                int pos = atomicAdd(&cnt, 1);
                if (pos < CAP) cand[pos] = k;
            }
        }
        __syncthreads();
        count = min(cnt, CAP);
    } else {
        // Dense fallback (dead in practice).
        for (int g = tid; g < TOT; g += 256) {
            float v = pv[g];
            if (v > 0.f) {
                unsigned bits = __float_as_uint(v);
                unsigned bin = ((bits - BINBASE) >> 15) + 1u;
                if (bin > NBIN - 1) bin = NBIN - 1;
                atomicAdd(&hist[bin], 1u);
            }
        }
        __syncthreads();
        const int base = tid * 8;
        int loc = 0;
        for (int k = 0; k < 8; ++k) loc += (int)hist[base + k];
        int sfx = loc;
        for (int off = 1; off < 64; off <<= 1) {
            int t = __shfl_down(sfx, off, 64);
            if (lane + off < 64) sfx += t;
        }
        if (lane == 0) wtot[wv] = sfx;
        __syncthreads();
        int crossSuf = 0;
        for (int w2 = wv + 1; w2 < 4; ++w2) crossSuf += wtot[w2];
        if (tid == 0) nztot = wtot[0] + wtot[1] + wtot[2] + wtot[3];
        {
            int S = (sfx - loc) + crossSuf;
            for (int k = 7; k >= 0; --k) {
                int binv = (int)hist[base + k];
                int Sk = S + binv;
                int bin = base + k;
                if (bin >= 1 && Sk >= MAXO && S < MAXO) cutbin = bin;
                S = Sk;
            }
        }
        __syncthreads();
        int B = (nztot >= MAXO) ? cutbin : 1;

        for (int g = tid; g < TOT; g += 256) {
            float v = pv[g];
            if (v > 0.f) {
                unsigned bits = __float_as_uint(v);
                unsigned bin = ((bits - BINBASE) >> 15) + 1u;
                if (bin > NBIN - 1) bin = NBIN - 1;
                if ((int)bin >= B) {
                    int pos = atomicAdd(&cnt, 1);
                    if (pos < CAP)
                        cand[pos] = ((u64)bits << 32)
                                  | (u64)(0xFFFFFFFFu - (unsigned)g);
                }
            }
        }
        __syncthreads();
        count = min(cnt, CAP);

        if (count < MAXO) {   // zero-fill, smallest flat index first
            if (tid == 0) {
                int c = count;
                for (int g = 0; g < TOT && c < MAXO; ++g) {
                    if (!(pv[g] > 0.f)) {
                        cand[c++] = (u64)(0xFFFFFFFFu - (unsigned)g);
                    }
                }
                cnt = c;
            }
            __syncthreads();
            count = min(cnt, CAP);
        }
    }

    u64 key;
    if (count <= 256) {
        key = (tid < count) ? cand[tid] : 0ull;
        key = regsort256(key, cand, tid);
    } else {
        int P = 256; while (P < count) P <<= 1;
        for (int i = count + tid; i < P; i += 256) cand[i] = 0ull;
        __syncthreads();
        bitonic_desc(cand, P, tid, 256);
        key = cand[tid];
    }

    if (tid < MAXO) {
        float sc      = __uint_as_float((unsigned)(key >> 32));
        unsigned flat = 0xFFFFFFFFu - (unsigned)(key & 0xFFFFFFFFull);
        int cls = (int)(flat / MAXO) + 1;
        const float4 bb =
            reinterpret_cast<const float4*>(pcBoxes)[(size_t)b * TOT + flat];
        reinterpret_cast<float4*>(out)[(size_t)b * MAXO + tid] = bb;
        out[(size_t)BATCH * MAXO * 4 + (size_t)b * MAXO + tid] = (float)cls;
        out[(size_t)BATCH * MAXO * 5 + (size_t)b * MAXO + tid] = sc;
    }
}

extern "C" void kernel_launch(void* const* d_in, const int* in_sizes, int n_in,
                              void* d_out, int out_size, void* d_ws,
                              size_t ws_size, hipStream_t stream) {
    const float* ploc   = (const float*)d_in[0];
    const float* plabel = (const float*)d_in[1];
    const float* dboxes = (const float*)d_in[2];
    float* out = (float*)d_out;

    float* ws      = (float*)d_ws;
    float* ltrb    = ws;                                   // B*N*4
    float* rowmax  = ltrb   + (size_t)BATCH * NANCH * 4;   // B*N
    float* rowsum  = rowmax + (size_t)BATCH * NANCH;       // B*N
    float* pcVals  = rowsum + (size_t)BATCH * NANCH;       // B*80*200
    float* pcBoxes = pcVals + (size_t)BATCH * C1 * MAXO;   // B*80*200*4
    int*   cntg    = (int*)(pcBoxes + (size_t)BATCH * C1 * MAXO * 4);
    int*   imgcnt  = cntg + BATCH * C1;                    // B ints
    char*  after   = (char*)(imgcnt + BATCH);
    u64* bucket = (u64*)(after + ((16 - (((size_t)after) & 15)) & 15));
    u64* imglist = bucket + (size_t)BATCH * C1 * CAPB;     // B * 16000 u64

    hipMemsetAsync(cntg, 0, (size_t)(BATCH * C1 + BATCH) * sizeof(int), stream);
    ssd_decode_stats<<<BATCH * NBLKA, APB, 0, stream>>>(
        ploc, plabel, dboxes, ltrb, rowmax, rowsum, cntg, bucket);
    ssd_class_nms<<<BATCH * C1, 256, 0, stream>>>(
        plabel, rowmax, rowsum, ltrb, cntg, bucket, pcVals, pcBoxes,
        imgcnt, imglist);
    ssd_final_topk<<<BATCH, 256, 0, stream>>>(
        pcVals, pcBoxes, imgcnt, imglist, out);
}

// Round 13
// 292.877 us; speedup vs baseline: 1.0363x; 1.0363x over previous
//
#include <hip/hip_runtime.h>
#include <math.h>

namespace {
constexpr int BATCH = 32;
constexpr int NANCH = 15130;
constexpr int NCLS  = 81;
constexpr int C1    = 80;          // foreground classes
constexpr int MAXO  = 200;
constexpr int APB   = 256;         // anchors per K1 block (= threads)
constexpr int NBLKA = (NANCH + APB - 1) / APB;   // 60
constexpr int CAPK2 = 512;         // K2 cand capacity (live path uses <=256)
constexpr int CAP   = 1024;        // K3 cand capacity
constexpr int CAPB  = 768;         // global bucket capacity (mean 434, sigma 20.5)
constexpr int NWORD = 4;           // 256 bits >= 200 for NMS bitmask
constexpr int NBIN  = 2048;        // histogram bins for K3 select
constexpr int NBINK2 = 768;        // K2 bins (shift 16); max used bin 641
constexpr unsigned BINBASE = 0x3D000000u;  // 0.03125f — below any score > 0.05
constexpr int IMGCAP = C1 * MAXO;  // 16000 — worst-case kept per image
}

#define SCORE_TH 0.05f
#define IOU_TH   0.5f

typedef unsigned long long u64;

__device__ __forceinline__ u64 shflx64(u64 v, int mask) {
    int lo = __shfl_xor((int)(unsigned)(v & 0xffffffffull), mask, 64);
    int hi = __shfl_xor((int)(unsigned)(v >> 32), mask, 64);
    return ((u64)(unsigned)hi << 32) | (unsigned)lo;
}

// Descending bitonic sort of P (power of 2) u64 keys in LDS (fallback path).
// Key = (float_bits(score) << 32) | (0xFFFFFFFF - index)
// => order: score desc, then index asc (matches jax.lax.top_k stability).
__device__ __forceinline__ void bitonic_desc(u64* keys, int P,
                                             int tid, int nthr) {
    for (int k = 2; k <= P; k <<= 1) {
        for (int j = k >> 1; j > 0; j >>= 1) {
            for (int i = tid; i < P; i += nthr) {
                int ixj = i ^ j;
                if (ixj > i) {
                    u64 a = keys[i], c = keys[ixj];
                    bool up = ((i & k) == 0);
                    if (up ? (a < c) : (a > c)) { keys[i] = c; keys[ixj] = a; }
                }
            }
            __syncthreads();
        }
    }
}

// Register bitonic sort of 256 keys (one per thread). j<64 phases via
// cross-lane shuffles; j in {64,128} via LDS round-trip. Same network.
__device__ __forceinline__ u64 regsort256(u64 key, u64* lds, int tid) {
    for (int k = 2; k <= 256; k <<= 1) {
        for (int j = k >> 1; j > 0; j >>= 1) {
            u64 pv;
            if (j < 64) {
                pv = shflx64(key, j);
            } else {
                lds[tid] = key;
                __syncthreads();
                pv = lds[tid ^ j];
            }
            bool up = ((tid & k) == 0);
            bool lt = ((tid & j) == 0);
            u64 mx = (key > pv) ? key : pv;
            u64 mn = (key > pv) ? pv : key;
            key = (up == lt) ? mx : mn;
            if (j >= 64) __syncthreads();
        }
    }
    return key;
}

// Kernel 1: one thread per anchor, 81 logits in registers. Exact reference
// op order throughout.
__global__ __launch_bounds__(256, 3) void ssd_decode_stats(
    const float* __restrict__ ploc, const float* __restrict__ plabel,
    const float* __restrict__ dboxes,
    float* __restrict__ ltrb, float* __restrict__ rowmax,
    float* __restrict__ rowsum,
    int* __restrict__ cntg, u64* __restrict__ bucket) {
#pragma clang fp contract(off)
    __shared__ int lcnt[C1], lbase[C1], lrank[C1];

    const int tid = threadIdx.x;
    const int b   = blockIdx.x / NBLKA;
    const int n0  = (blockIdx.x % NBLKA) * APB;
    const int n   = n0 + tid;
    const bool act = (n < NANCH);

    if (tid < C1) lcnt[tid] = 0;

    float x[NCLS];
    if (act) {
        const float* pl = ploc + (size_t)b * 4 * NANCH + n;
        float px = pl[0], py = pl[NANCH], pw = pl[2 * NANCH],
              ph = pl[3 * NANCH];
        float4 db = reinterpret_cast<const float4*>(dboxes)[n];
        float cx = px * 0.1f * db.z + db.x;
        float cy = py * 0.1f * db.w + db.y;
        float w  = expf(pw * 0.2f) * db.z;
        float h  = expf(ph * 0.2f) * db.w;
        float4 o;
        o.x = cx - 0.5f * w; o.y = cy - 0.5f * h;
        o.z = cx + 0.5f * w; o.w = cy + 0.5f * h;
        reinterpret_cast<float4*>(ltrb)[(size_t)b * NANCH + n] = o;

        const float* pb = plabel + (size_t)b * NCLS * NANCH + n;
#pragma unroll
        for (int c = 0; c < NCLS; ++c) x[c] = pb[(size_t)c * NANCH];

        float m = -INFINITY;
#pragma unroll
        for (int c = 0; c < NCLS; ++c) m = fmaxf(m, x[c]);
#pragma unroll
        for (int c = 0; c < NCLS; ++c) x[c] = expf(x[c] - m);
        float s = 0.f;
#pragma unroll
        for (int c = 0; c < NCLS; ++c) s += x[c];   // serial, reference order
        rowmax[(size_t)b * NANCH + n] = m;
        rowsum[(size_t)b * NANCH + n] = s;

#pragma unroll
        for (int c = 1; c < NCLS; ++c) {
            x[c] = x[c] / s;   // exact IEEE div = reference value
            if (x[c] > SCORE_TH) atomicAdd(&lcnt[c - 1], 1);
        }
    }
    __syncthreads();

    if (tid < C1) {
        int cn = lcnt[tid];
        lbase[tid] = (cn > 0) ? atomicAdd(&cntg[b * C1 + tid], cn) : 0;
        lrank[tid] = 0;
    }
    __syncthreads();

    if (act) {
#pragma unroll
        for (int c = 1; c < NCLS; ++c) {
            if (x[c] > SCORE_TH) {
                int r = atomicAdd(&lrank[c - 1], 1);
                int pos = lbase[c - 1] + r;
                if (pos < CAPB)
                    bucket[(size_t)(b * C1 + (c - 1)) * CAPB + pos] =
                        ((u64)__float_as_uint(x[c]) << 32)
                        | (u64)(0xFFFFFFFFu - (unsigned)n);
            }
        }
    }
}

// Kernel 2: per (b, class): histogram-select ~top-200, register bitonic sort,
// SINGLE-WAVE lazy NMS: wave 0 runs the greedy recurrence with zero block
// barriers; each iteration processes one surviving row i (columns in
// registers, row words via ballot). Exact reference recurrence.
__global__ __launch_bounds__(256, 8) void ssd_class_nms(
    const float* __restrict__ plabel, const float* __restrict__ rowmax,
    const float* __restrict__ rowsum, const float* __restrict__ ltrb,
    const int* __restrict__ cntg, const u64* __restrict__ bucket,
    float* __restrict__ pcVals, float* __restrict__ pcBoxes,
    int* __restrict__ imgcnt, u64* __restrict__ imglist) {
    __shared__ u64 cand[CAPK2];               // 4 KB
    __shared__ unsigned int hist[NBINK2];     // 3 KB (reused as fill scratch)
    __shared__ float4 box4[MAXO];             // 3.2 KB
    __shared__ float areas[MAXO], vs[MAXO];   // 1.6 KB
    __shared__ u64 keepw[NWORD], vmaskS[NWORD];
    __shared__ int wtot[4];
    __shared__ int cnt, fillcnt, cutbin, kcnt, kbase;

    const int tid  = threadIdx.x;
    const int lane = tid & 63;
    const int wv   = tid >> 6;
    const int b    = blockIdx.x / C1;
    const int cls  = blockIdx.x % C1 + 1;   // skip background
    const int bc   = b * C1 + (cls - 1);

    for (int i = tid; i < NBINK2; i += 256) hist[i] = 0u;
    if (tid == 0) { cnt = 0; fillcnt = 0; cutbin = 1; kcnt = 0; }
    __syncthreads();

    const float* pl = plabel + ((size_t)b * NCLS + cls) * NANCH;
    const float* rm = rowmax + (size_t)b * NANCH;
    const float* rs = rowsum + (size_t)b * NANCH;
    const u64* bkt = bucket + (size_t)bc * CAPB;

    const int gcount = cntg[bc];
    const bool ovf = (gcount > CAPB);   // uniform; dead in practice
    int gathered;

    if (!ovf) {
        const int count = gcount;
        // Pass 1: histogram (bin = ((bits-BINBASE)>>16)+1, monotone in value).
        for (int i = tid; i < count; i += 256) {
            unsigned bits = (unsigned)(bkt[i] >> 32);
            unsigned bin = ((bits - BINBASE) >> 16) + 1u;
            if (bin > NBINK2 - 1) bin = NBINK2 - 1;
            atomicAdd(&hist[bin], 1u);
        }
        __syncthreads();

        // Per-thread group sum (3 bins), wave suffix-scan, cross-wave combine.
        const int base = tid * 3;
        int loc = (int)hist[base] + (int)hist[base + 1] + (int)hist[base + 2];
        int sfx = loc;
        for (int off = 1; off < 64; off <<= 1) {
            int t = __shfl_down(sfx, off, 64);
            if (lane + off < 64) sfx += t;
        }
        if (lane == 0) wtot[wv] = sfx;
        __syncthreads();
        int crossSuf = 0;
        for (int w2 = wv + 1; w2 < 4; ++w2) crossSuf += wtot[w2];
        const int nztot = wtot[0] + wtot[1] + wtot[2] + wtot[3];
        {
            int S = (sfx - loc) + crossSuf;
            for (int k = 2; k >= 0; --k) {
                int binv = (int)hist[base + k];
                int Sk = S + binv;
                int bin = base + k;
                if (bin >= 1 && Sk >= MAXO && S < MAXO) cutbin = bin;
                S = Sk;
            }
        }
        __syncthreads();
        const int B = (nztot >= MAXO) ? cutbin : 1;

        // Pass 2: gather keys with bin >= B (top-200 subset; ~205 items).
        for (int i = tid; i < count; i += 256) {
            u64 k = bkt[i];
            unsigned bits = (unsigned)(k >> 32);
            unsigned bin = ((bits - BINBASE) >> 16) + 1u;
            if (bin > NBINK2 - 1) bin = NBINK2 - 1;
            if ((int)bin >= B) {
                int pos = atomicAdd(&cnt, 1);
                if (pos < CAPK2) cand[pos] = k;
            }
        }
        __syncthreads();
        gathered = min(cnt, CAPK2);
    } else {
        // Overflow fallback (dead): full rescan, no select.
        for (int n = tid; n < NANCH; n += 256) {
            float p = expf(pl[n] - rm[n]) / rs[n];
            if (p > SCORE_TH) {
                int pos = atomicAdd(&cnt, 1);
                if (pos < CAPK2)
                    cand[pos] = ((u64)__float_as_uint(p) << 32)
                              | (u64)(0xFFFFFFFFu - (unsigned)n);
            }
        }
        __syncthreads();
        gathered = min(cnt, CAPK2);
    }

    u64 key;
    if (gathered <= 256) {
        key = (tid < gathered) ? cand[tid] : 0ull;
        key = regsort256(key, cand, tid);
    } else {
        for (int i = gathered + tid; i < CAPK2; i += 256) cand[i] = 0ull;
        __syncthreads();
        bitonic_desc(cand, CAPK2, tid, 256);
        key = cand[tid];
    }

    // <200 positives: fill with smallest anchor idx (top_k zero tie-break). Dead.
    if (gathered < MAXO) {
        int* scanb = (int*)hist;
        cand[tid] = key;
        __syncthreads();
        const int need = MAXO - gathered;
        for (int base2 = 0; base2 < NANCH; base2 += 256) {
            if (fillcnt >= need) break;
            int n = base2 + tid;
            int flag = 0;
            if (n < NANCH) {
                float p = expf(pl[n] - rm[n]) / rs[n];
                flag = (p <= SCORE_TH) ? 1 : 0;
            }
            scanb[tid] = flag;
            __syncthreads();
            for (int off = 1; off < 256; off <<= 1) {
                int v  = scanb[tid];
                int vp = (tid >= off) ? scanb[tid - off] : 0;
                __syncthreads();
                scanb[tid] = v + vp;
                __syncthreads();
            }
            int excl = scanb[tid] - flag;
            if (flag && (fillcnt + excl) < need)
                cand[gathered + fillcnt + excl] =
                    (u64)(0xFFFFFFFFu - (unsigned)n);
            __syncthreads();
            if (tid == 0) fillcnt += scanb[255];
            __syncthreads();
        }
        __syncthreads();
        key = cand[tid];
    }

    // Gather top-200 boxes/scores into LDS + per-thread registers.
    float4 bjr = make_float4(0.f, 0.f, 0.f, 0.f);
    float vsr = 0.f;
    if (tid < MAXO) {
#pragma clang fp contract(off)
        vsr = __uint_as_float((unsigned)(key >> 32));
        unsigned n = 0xFFFFFFFFu - (unsigned)(key & 0xFFFFFFFFull);
        bjr = reinterpret_cast<const float4*>(ltrb)[(size_t)b * NANCH + n];
        box4[tid] = bjr;
        areas[tid] = (bjr.z - bjr.x) * (bjr.w - bjr.y);
        vs[tid] = vsr;
    }
    {
        bool pred = (tid < MAXO) && (vsr > 0.f);
        u64 bal = __ballot(pred);
        if (lane == 0) vmaskS[wv] = bal;
    }
    __syncthreads();

    // Single-wave lazy greedy NMS (wave 0 only, no block barriers inside).
    // Lane l owns columns l, l+64, l+128, l+192. Each iteration: one
    // surviving row i, 4 IoUs/lane, 4 ballots = the row's 4 words.
    // Identical recurrence to the reference fori_loop.
    if (wv == 0) {
#pragma clang fp contract(off)
        const float4 b0 = box4[lane];
        const float4 b1 = box4[64 + lane];
        const float4 b2 = box4[128 + lane];
        const bool   j3v = (lane < MAXO - 192);
        const float4 b3 = box4[j3v ? 192 + lane : 0];
        const float a0 = areas[lane];
        const float a1 = areas[64 + lane];
        const float a2 = areas[128 + lane];
        const float a3 = areas[j3v ? 192 + lane : 0];
        const u64 v0 = vmaskS[0], v1 = vmaskS[1],
                  v2 = vmaskS[2], v3 = vmaskS[3];
        u64 k0 = ~0ull, k1 = ~0ull, k2 = ~0ull, k3 = ~0ull;

        int i;
        {
            u64 c; i = -1;
            if ((c = k0 & v0))      i = __builtin_ctzll(c);
            else if ((c = k1 & v1)) i = 64 + __builtin_ctzll(c);
            else if ((c = k2 & v2)) i = 128 + __builtin_ctzll(c);
            else if ((c = k3 & v3)) i = 192 + __builtin_ctzll(c);
        }
        while (i >= 0) {
            const float4 bi = box4[i];     // broadcast LDS read
            const float ai = areas[i];     // broadcast LDS read
            float l0 = fmaxf(bi.x, b0.x), t0 = fmaxf(bi.y, b0.y);
            float r0 = fminf(bi.z, b0.z), d0 = fminf(bi.w, b0.w);
            float in0 = fmaxf(r0 - l0, 0.f) * fmaxf(d0 - t0, 0.f);
            bool s0p = (in0 / (ai + a0 - in0 + 1e-12f)) >= IOU_TH;
            float l1 = fmaxf(bi.x, b1.x), t1 = fmaxf(bi.y, b1.y);
            float r1 = fminf(bi.z, b1.z), d1 = fminf(bi.w, b1.w);
            float in1 = fmaxf(r1 - l1, 0.f) * fmaxf(d1 - t1, 0.f);
            bool s1p = (in1 / (ai + a1 - in1 + 1e-12f)) >= IOU_TH;
            float l2 = fmaxf(bi.x, b2.x), t2_ = fmaxf(bi.y, b2.y);
            float r2 = fminf(bi.z, b2.z), d2 = fminf(bi.w, b2.w);
            float in2 = fmaxf(r2 - l2, 0.f) * fmaxf(d2 - t2_, 0.f);
            bool s2p = (in2 / (ai + a2 - in2 + 1e-12f)) >= IOU_TH;
            float l3 = fmaxf(bi.x, b3.x), t3 = fmaxf(bi.y, b3.y);
            float r3 = fminf(bi.z, b3.z), d3 = fminf(bi.w, b3.w);
            float in3 = fmaxf(r3 - l3, 0.f) * fmaxf(d3 - t3, 0.f);
            bool s3p = (in3 / (ai + a3 - in3 + 1e-12f)) >= IOU_TH;

            u64 s0 = __ballot(s0p && (lane > i));
            u64 s1 = __ballot(s1p && (64 + lane > i));
            u64 s2 = __ballot(s2p && (128 + lane > i));
            u64 s3 = __ballot(s3p && j3v && (192 + lane > i));
            k0 &= ~s0; k1 &= ~s1; k2 &= ~s2; k3 &= ~s3;

            int w = i >> 6, bit = i & 63;
            u64 above = (bit == 63) ? 0ull : (~0ull << (bit + 1));
            u64 cur = ((w == 0) ? (k0 & v0) : (w == 1) ? (k1 & v1)
                       : (w == 2) ? (k2 & v2) : (k3 & v3)) & above;
            i = -1;
            while (true) {
                if (cur) { i = w * 64 + __builtin_ctzll(cur); break; }
                if (++w >= 4) break;
                cur = (w == 1) ? (k1 & v1) : (w == 2) ? (k2 & v2) : (k3 & v3);
            }
        }
        if (lane == 0) {
            keepw[0] = k0; keepw[1] = k1; keepw[2] = k2; keepw[3] = k3;
        }
    }
    __syncthreads();

    bool kp = false;
    if (tid < MAXO) {
        kp = (keepw[tid >> 6] >> (tid & 63)) & 1ull;
        pcVals[(size_t)bc * MAXO + tid] = (kp && vsr > 0.f) ? vsr : 0.f;
        reinterpret_cast<float4*>(pcBoxes + (size_t)bc * MAXO * 4)[tid] = bjr;
    }

    // Compact kept keys into the per-image list (set-equal to dense nonzeros).
    bool keep_me = (tid < MAXO) && kp && (vsr > 0.f);
    int r = -1;
    if (keep_me) r = atomicAdd(&kcnt, 1);
    __syncthreads();
    if (tid == 0) kbase = (kcnt > 0) ? atomicAdd(&imgcnt[b], kcnt) : 0;
    __syncthreads();
    if (keep_me) {
        unsigned g = (unsigned)((cls - 1) * MAXO + tid);
        imglist[(size_t)b * IMGCAP + kbase + r] =
            ((u64)__float_as_uint(vsr) << 32) | (u64)(0xFFFFFFFFu - g);
    }
}

// Kernel 3: per image, exact top-200. Live path reads the compact kept list
// (~2-4k entries); dense fallback (NZ<200) kept verbatim.
__global__ __launch_bounds__(256) void ssd_final_topk(
    const float* __restrict__ pcVals, const float* __restrict__ pcBoxes,
    const int* __restrict__ imgcnt, const u64* __restrict__ imglist,
    float* __restrict__ out) {
    __shared__ unsigned int hist[NBIN];
    __shared__ u64 cand[CAP];
    __shared__ int wtot[4];
    __shared__ int cnt, cutbin, nztot;

    const int tid  = threadIdx.x;
    const int lane = tid & 63;
    const int wv   = tid >> 6;
    const int b    = blockIdx.x;
    const int TOT  = C1 * MAXO;   // 16000
    const float* pv = pcVals + (size_t)b * TOT;
    const int NZ   = imgcnt[b];

    for (int i = tid; i < NBIN; i += 256) hist[i] = 0u;
    if (tid == 0) { cnt = 0; cutbin = 1; }
    __syncthreads();

    int count;
    if (NZ >= MAXO) {
        const u64* lst = imglist + (size_t)b * IMGCAP;
        for (int i = tid; i < NZ; i += 256) {
            unsigned bits = (unsigned)(lst[i] >> 32);
            unsigned bin = ((bits - BINBASE) >> 15) + 1u;
            if (bin > NBIN - 1) bin = NBIN - 1;
            atomicAdd(&hist[bin], 1u);
        }
        __syncthreads();

        const int base = tid * 8;
        int loc = 0;
        for (int k = 0; k < 8; ++k) loc += (int)hist[base + k];
        int sfx = loc;
        for (int off = 1; off < 64; off <<= 1) {
            int t = __shfl_down(sfx, off, 64);
            if (lane + off < 64) sfx += t;
        }
        if (lane == 0) wtot[wv] = sfx;
        __syncthreads();
        int crossSuf = 0;
        for (int w2 = wv + 1; w2 < 4; ++w2) crossSuf += wtot[w2];
        {
            int S = (sfx - loc) + crossSuf;
            for (int k = 7; k >= 0; --k) {
                int binv = (int)hist[base + k];
                int Sk = S + binv;
                int bin = base + k;
                if (bin >= 1 && Sk >= MAXO && S < MAXO) cutbin = bin;
                S = Sk;
            }
        }
        __syncthreads();
        const int B = cutbin;

        for (int i = tid; i < NZ; i += 256) {
            u64 k = lst[i];
            unsigned bits = (unsigned)(k >> 32);
            unsigned bin = ((bits - BINBASE) >> 15) + 1u;
            if (bin > NBIN - 1) bin = NBIN - 1;
            if ((int)bin >= B) {
                int pos = atomicAdd(&cnt, 1);
                if (pos < CAP) cand[pos] = k;
            }
        }
        __syncthreads();
        count = min(cnt, CAP);
    } else {
        // Dense fallback (dead in practice).
        for (int g = tid; g < TOT; g += 256) {
            float v = pv[g];
            if (v > 0.f) {
                unsigned bits = __float_as_uint(v);
                unsigned bin = ((bits - BINBASE) >> 15) + 1u;
                if (bin > NBIN - 1) bin = NBIN - 1;
                atomicAdd(&hist[bin], 1u);
            }
        }
        __syncthreads();
        const int base = tid * 8;
        int loc = 0;
        for (int k = 0; k < 8; ++k) loc += (int)hist[base + k];
        int sfx = loc;
        for (int off = 1; off < 64; off <<= 1) {
            int t = __shfl_down(sfx, off, 64);
            if (lane + off < 64) sfx += t;
        }
        if (lane == 0) wtot[wv] = sfx;
        __syncthreads();
        int crossSuf = 0;
        for (int w2 = wv + 1; w2 < 4; ++w2) crossSuf += wtot[w2];
        if (tid == 0) nztot = wtot[0] + wtot[1] + wtot[2] + wtot[3];
        {
            int S = (sfx - loc) + crossSuf;
            for (int k = 7; k >= 0; --k) {
                int binv = (int)hist[base + k];
                int Sk = S + binv;
                int bin = base + k;
                if (bin >= 1 && Sk >= MAXO && S < MAXO) cutbin = bin;
                S = Sk;
            }
        }
        __syncthreads();
        int B = (nztot >= MAXO) ? cutbin : 1;

        for (int g = tid; g < TOT; g += 256) {
            float v = pv[g];
            if (v > 0.f) {
                unsigned bits = __float_as_uint(v);
                unsigned bin = ((bits - BINBASE) >> 15) + 1u;
                if (bin > NBIN - 1) bin = NBIN - 1;
                if ((int)bin >= B) {
                    int pos = atomicAdd(&cnt, 1);
                    if (pos < CAP)
                        cand[pos] = ((u64)bits << 32)
                                  | (u64)(0xFFFFFFFFu - (unsigned)g);
                }
            }
        }
        __syncthreads();
        count = min(cnt, CAP);

        if (count < MAXO) {   // zero-fill, smallest flat index first
            if (tid == 0) {
                int c = count;
                for (int g = 0; g < TOT && c < MAXO; ++g) {
                    if (!(pv[g] > 0.f)) {
                        cand[c++] = (u64)(0xFFFFFFFFu - (unsigned)g);
                    }
                }
                cnt = c;
            }
            __syncthreads();
            count = min(cnt, CAP);
        }
    }

    u64 key;
    if (count <= 256) {
        key = (tid < count) ? cand[tid] : 0ull;
        key = regsort256(key, cand, tid);
    } else {
        int P = 256; while (P < count) P <<= 1;
        for (int i = count + tid; i < P; i += 256) cand[i] = 0ull;
        __syncthreads();
        bitonic_desc(cand, P, tid, 256);
        key = cand[tid];
    }

    if (tid < MAXO) {
        float sc      = __uint_as_float((unsigned)(key >> 32));
        unsigned flat = 0xFFFFFFFFu - (unsigned)(key & 0xFFFFFFFFull);
        int cls = (int)(flat / MAXO) + 1;
        const float4 bb =
            reinterpret_cast<const float4*>(pcBoxes)[(size_t)b * TOT + flat];
        reinterpret_cast<float4*>(out)[(size_t)b * MAXO + tid] = bb;
        out[(size_t)BATCH * MAXO * 4 + (size_t)b * MAXO + tid] = (float)cls;
        out[(size_t)BATCH * MAXO * 5 + (size_t)b * MAXO + tid] = sc;
    }
}

extern "C" void kernel_launch(void* const* d_in, const int* in_sizes, int n_in,
                              void* d_out, int out_size, void* d_ws,
                              size_t ws_size, hipStream_t stream) {
    const float* ploc   = (const float*)d_in[0];
    const float* plabel = (const float*)d_in[1];
    const float* dboxes = (const float*)d_in[2];
    float* out = (float*)d_out;

    float* ws      = (float*)d_ws;
    float* ltrb    = ws;                                   // B*N*4
    float* rowmax  = ltrb   + (size_t)BATCH * NANCH * 4;   // B*N
    float* rowsum  = rowmax + (size_t)BATCH * NANCH;       // B*N
    float* pcVals  = rowsum + (size_t)BATCH * NANCH;       // B*80*200
    float* pcBoxes = pcVals + (size_t)BATCH * C1 * MAXO;   // B*80*200*4
    int*   cntg    = (int*)(pcBoxes + (size_t)BATCH * C1 * MAXO * 4);
    int*   imgcnt  = cntg + BATCH * C1;                    // B ints
    char*  after   = (char*)(imgcnt + BATCH);
    u64* bucket = (u64*)(after + ((16 - (((size_t)after) & 15)) & 15));
    u64* imglist = bucket + (size_t)BATCH * C1 * CAPB;     // B * 16000 u64

    hipMemsetAsync(cntg, 0, (size_t)(BATCH * C1 + BATCH) * sizeof(int), stream);
    ssd_decode_stats<<<BATCH * NBLKA, APB, 0, stream>>>(
        ploc, plabel, dboxes, ltrb, rowmax, rowsum, cntg, bucket);
    ssd_class_nms<<<BATCH * C1, 256, 0, stream>>>(
        plabel, rowmax, rowsum, ltrb, cntg, bucket, pcVals, pcBoxes,
        imgcnt, imglist);
    ssd_final_topk<<<BATCH, 256, 0, stream>>>(
        pcVals, pcBoxes, imgcnt, imglist, out);
}

// Round 14
// 245.085 us; speedup vs baseline: 1.2383x; 1.1950x over previous
//
#include <hip/hip_runtime.h>
#include <math.h>

namespace {
constexpr int BATCH = 32;
constexpr int NANCH = 15130;
constexpr int NCLS  = 81;
constexpr int C1    = 80;          // foreground classes
constexpr int MAXO  = 200;
constexpr int APB   = 256;         // anchors per K1 block (= threads)
constexpr int NBLKA = (NANCH + APB - 1) / APB;   // 60
constexpr int CAPK2 = 512;         // K2 cand capacity (live path uses <=256)
constexpr int CAP   = 1024;        // K3 cand capacity
constexpr int CAPB  = 768;         // global bucket capacity (mean 434, sigma 20.5)
constexpr int NBIN  = 2048;        // histogram bins for K3 select
constexpr int NBINK2 = 768;        // K2 bins (shift 16); max used bin 641
constexpr unsigned BINBASE = 0x3D000000u;  // 0.03125f — below any score > 0.05
constexpr int IMGCAP = C1 * MAXO;  // 16000 — worst-case kept per image
}

#define SCORE_TH 0.05f
#define IOU_TH   0.5f

typedef unsigned long long u64;

__device__ __forceinline__ u64 shflx64(u64 v, int mask) {
    int lo = __shfl_xor((int)(unsigned)(v & 0xffffffffull), mask, 64);
    int hi = __shfl_xor((int)(unsigned)(v >> 32), mask, 64);
    return ((u64)(unsigned)hi << 32) | (unsigned)lo;
}

// Descending bitonic sort of P (power of 2) u64 keys in LDS (fallback path).
// Key = (float_bits(score) << 32) | (0xFFFFFFFF - index)
// => order: score desc, then index asc (matches jax.lax.top_k stability).
__device__ __forceinline__ void bitonic_desc(u64* keys, int P,
                                             int tid, int nthr) {
    for (int k = 2; k <= P; k <<= 1) {
        for (int j = k >> 1; j > 0; j >>= 1) {
            for (int i = tid; i < P; i += nthr) {
                int ixj = i ^ j;
                if (ixj > i) {
                    u64 a = keys[i], c = keys[ixj];
                    bool up = ((i & k) == 0);
                    if (up ? (a < c) : (a > c)) { keys[i] = c; keys[ixj] = a; }
                }
            }
            __syncthreads();
        }
    }
}

// Register bitonic sort of 256 keys (one per thread, 256-thread blocks).
// Used by K3. j<64 via shuffles; j in {64,128} via LDS round-trip.
__device__ __forceinline__ u64 regsort256(u64 key, u64* lds, int tid) {
    for (int k = 2; k <= 256; k <<= 1) {
        for (int j = k >> 1; j > 0; j >>= 1) {
            u64 pv;
            if (j < 64) {
                pv = shflx64(key, j);
            } else {
                lds[tid] = key;
                __syncthreads();
                pv = lds[tid ^ j];
            }
            bool up = ((tid & k) == 0);
            bool lt = ((tid & j) == 0);
            u64 mx = (key > pv) ? key : pv;
            u64 mn = (key > pv) ? pv : key;
            key = (up == lt) ? mx : mn;
            if (j >= 64) __syncthreads();
        }
    }
    return key;
}

// Kernel 1: one thread per anchor, 81 logits in registers. Exact reference
// op order throughout.
__global__ __launch_bounds__(256, 3) void ssd_decode_stats(
    const float* __restrict__ ploc, const float* __restrict__ plabel,
    const float* __restrict__ dboxes,
    float* __restrict__ ltrb, float* __restrict__ rowmax,
    float* __restrict__ rowsum,
    int* __restrict__ cntg, u64* __restrict__ bucket) {
#pragma clang fp contract(off)
    __shared__ int lcnt[C1], lbase[C1], lrank[C1];

    const int tid = threadIdx.x;
    const int b   = blockIdx.x / NBLKA;
    const int n0  = (blockIdx.x % NBLKA) * APB;
    const int n   = n0 + tid;
    const bool act = (n < NANCH);

    if (tid < C1) lcnt[tid] = 0;

    float x[NCLS];
    if (act) {
        const float* pl = ploc + (size_t)b * 4 * NANCH + n;
        float px = pl[0], py = pl[NANCH], pw = pl[2 * NANCH],
              ph = pl[3 * NANCH];
        float4 db = reinterpret_cast<const float4*>(dboxes)[n];
        float cx = px * 0.1f * db.z + db.x;
        float cy = py * 0.1f * db.w + db.y;
        float w  = expf(pw * 0.2f) * db.z;
        float h  = expf(ph * 0.2f) * db.w;
        float4 o;
        o.x = cx - 0.5f * w; o.y = cy - 0.5f * h;
        o.z = cx + 0.5f * w; o.w = cy + 0.5f * h;
        reinterpret_cast<float4*>(ltrb)[(size_t)b * NANCH + n] = o;

        const float* pb = plabel + (size_t)b * NCLS * NANCH + n;
#pragma unroll
        for (int c = 0; c < NCLS; ++c) x[c] = pb[(size_t)c * NANCH];

        float m = -INFINITY;
#pragma unroll
        for (int c = 0; c < NCLS; ++c) m = fmaxf(m, x[c]);
#pragma unroll
        for (int c = 0; c < NCLS; ++c) x[c] = expf(x[c] - m);
        float s = 0.f;
#pragma unroll
        for (int c = 0; c < NCLS; ++c) s += x[c];   // serial, reference order
        rowmax[(size_t)b * NANCH + n] = m;
        rowsum[(size_t)b * NANCH + n] = s;

#pragma unroll
        for (int c = 1; c < NCLS; ++c) {
            x[c] = x[c] / s;   // exact IEEE div = reference value
            if (x[c] > SCORE_TH) atomicAdd(&lcnt[c - 1], 1);
        }
    }
    __syncthreads();

    if (tid < C1) {
        int cn = lcnt[tid];
        lbase[tid] = (cn > 0) ? atomicAdd(&cntg[b * C1 + tid], cn) : 0;
        lrank[tid] = 0;
    }
    __syncthreads();

    if (act) {
#pragma unroll
        for (int c = 1; c < NCLS; ++c) {
            if (x[c] > SCORE_TH) {
                int r = atomicAdd(&lrank[c - 1], 1);
                int pos = lbase[c - 1] + r;
                if (pos < CAPB)
                    bucket[(size_t)(b * C1 + (c - 1)) * CAPB + pos] =
                        ((u64)__float_as_uint(x[c]) << 32)
                        | (u64)(0xFFFFFFFFu - (unsigned)n);
            }
        }
    }
}

// Kernel 2: ONE WAVE per (b, class). Histogram-select, in-register bitonic
// sort (4 keys/lane, zero LDS/barriers), lazy single-wave NMS (exact
// reference greedy recurrence), ballot-ranked compact output.
__global__ __launch_bounds__(64) void ssd_class_nms(
    const float* __restrict__ plabel, const float* __restrict__ rowmax,
    const float* __restrict__ rowsum, const float* __restrict__ ltrb,
    const int* __restrict__ cntg, const u64* __restrict__ bucket,
    float* __restrict__ pcVals, float* __restrict__ pcBoxes,
    int* __restrict__ imgcnt, u64* __restrict__ imglist) {
    __shared__ u64 cand[CAPK2];               // 4 KB
    __shared__ unsigned int hist[NBINK2];     // 3 KB
    __shared__ float4 box4[MAXO];             // 3.2 KB
    __shared__ float areas[MAXO];             // 0.8 KB
    __shared__ int cnt, cutbin;

    const int lane = threadIdx.x;             // 0..63, one wave
    const int b    = blockIdx.x / C1;
    const int cls  = blockIdx.x % C1 + 1;     // skip background
    const int bc   = b * C1 + (cls - 1);

    for (int i = lane; i < NBINK2; i += 64) hist[i] = 0u;
    if (lane == 0) { cnt = 0; cutbin = 1; }
    __syncthreads();

    const float* pl = plabel + ((size_t)b * NCLS + cls) * NANCH;
    const float* rm = rowmax + (size_t)b * NANCH;
    const float* rs = rowsum + (size_t)b * NANCH;
    const u64* bkt = bucket + (size_t)bc * CAPB;

    const int gcount = cntg[bc];
    const bool ovf = (gcount > CAPB);   // uniform; dead in practice
    int gathered;

    if (!ovf) {
        // Pass 1: histogram (bin = ((bits-BINBASE)>>16)+1, monotone in value).
        for (int i = lane; i < gcount; i += 64) {
            unsigned bits = (unsigned)(bkt[i] >> 32);
            unsigned bin = ((bits - BINBASE) >> 16) + 1u;
            if (bin > NBINK2 - 1) bin = NBINK2 - 1;
            atomicAdd(&hist[bin], 1u);
        }
        __syncthreads();

        // Lane owns 12 bins; wave suffix-scan via shfl_down.
        const int base = lane * 12;
        int loc = 0;
#pragma unroll
        for (int k = 0; k < 12; ++k) loc += (int)hist[base + k];
        int sfx = loc;
        for (int off = 1; off < 64; off <<= 1) {
            int t = __shfl_down(sfx, off, 64);
            if (lane + off < 64) sfx += t;
        }
        const int nztot = __shfl(sfx, 0);
        {
            int S = sfx - loc;   // suffix strictly beyond my 12-bin group
            for (int k = 11; k >= 0; --k) {
                int binv = (int)hist[base + k];
                int Sk = S + binv;
                int bin = base + k;
                if (bin >= 1 && Sk >= MAXO && S < MAXO) cutbin = bin;
                S = Sk;
            }
        }
        __syncthreads();
        const int B = (nztot >= MAXO) ? cutbin : 1;

        // Pass 2: gather keys with bin >= B (top-200 subset; ~205 items).
        for (int i = lane; i < gcount; i += 64) {
            u64 k = bkt[i];
            unsigned bits = (unsigned)(k >> 32);
            unsigned bin = ((bits - BINBASE) >> 16) + 1u;
            if (bin > NBINK2 - 1) bin = NBINK2 - 1;
            if ((int)bin >= B) {
                int pos = atomicAdd(&cnt, 1);
                if (pos < CAPK2) cand[pos] = k;
            }
        }
        __syncthreads();
        gathered = min(cnt, CAPK2);
    } else {
        // Overflow fallback (dead): full rescan, no select.
        for (int n = lane; n < NANCH; n += 64) {
            float p = expf(pl[n] - rm[n]) / rs[n];
            if (p > SCORE_TH) {
                int pos = atomicAdd(&cnt, 1);
                if (pos < CAPK2)
                    cand[pos] = ((u64)__float_as_uint(p) << 32)
                              | (u64)(0xFFFFFFFFu - (unsigned)n);
            }
        }
        __syncthreads();
        gathered = min(cnt, CAPK2);
    }

    // ---- sort: element e = s*64 + lane lives in register r_s of lane ----
    u64 r0, r1, r2, r3;
    if (gathered <= 256) {
        r0 = (lane < gathered) ? cand[lane] : 0ull;
        r1 = (64 + lane < gathered) ? cand[64 + lane] : 0ull;
        r2 = (128 + lane < gathered) ? cand[128 + lane] : 0ull;
        r3 = (192 + lane < gathered) ? cand[192 + lane] : 0ull;

        // In-register bitonic (descending), identical network to regsort256.
        auto SH = [&](u64& rr, int j, bool up) {
            u64 pv = shflx64(rr, j);
            bool lt = ((lane & j) == 0);
            u64 mx = (rr > pv) ? rr : pv;
            u64 mn = (rr > pv) ? pv : rr;
            rr = (up == lt) ? mx : mn;
        };
        auto CE = [](u64& a, u64& c, bool up) {   // a = smaller index
            u64 mx = (a > c) ? a : c;
            u64 mn = (a > c) ? c : a;
            a = up ? mx : mn;
            c = up ? mn : mx;
        };
        // k = 2..32: up depends on lane only (e&k == lane&k)
        for (int k = 2; k <= 32; k <<= 1) {
            for (int j = k >> 1; j > 0; j >>= 1) {
                bool up = ((lane & k) == 0);
                SH(r0, j, up); SH(r1, j, up); SH(r2, j, up); SH(r3, j, up);
            }
        }
        // k = 64: up = ((e&64)==0) -> slot even
        for (int j = 32; j > 0; j >>= 1) {
            SH(r0, j, true); SH(r1, j, false); SH(r2, j, true); SH(r3, j, false);
        }
        // k = 128: j=64 cross-slot, then j<64; up = ((e&128)==0) -> s<2
        CE(r0, r1, true); CE(r2, r3, false);
        for (int j = 32; j > 0; j >>= 1) {
            SH(r0, j, true); SH(r1, j, true); SH(r2, j, false); SH(r3, j, false);
        }
        // k = 256: up = true everywhere
        CE(r0, r2, true); CE(r1, r3, true);
        CE(r0, r1, true); CE(r2, r3, true);
        for (int j = 32; j > 0; j >>= 1) {
            SH(r0, j, true); SH(r1, j, true); SH(r2, j, true); SH(r3, j, true);
        }
    } else {
        // Fallback (dead): LDS bitonic over 512.
        for (int i = gathered + lane; i < CAPK2; i += 64) cand[i] = 0ull;
        __syncthreads();
        bitonic_desc(cand, CAPK2, lane, 64);
        r0 = cand[lane]; r1 = cand[64 + lane];
        r2 = cand[128 + lane]; r3 = cand[192 + lane];
    }

    // <200 positives: fill with smallest anchor idx (top_k zero tie-break). Dead.
    if (gathered < MAXO) {
        cand[lane] = r0; cand[64 + lane] = r1;
        cand[128 + lane] = r2; cand[192 + lane] = r3;
        __syncthreads();
        const int need = MAXO - gathered;
        int fillcnt = 0;   // wave-uniform
        for (int base2 = 0; base2 < NANCH && fillcnt < need; base2 += 64) {
            int n = base2 + lane;
            bool flag = false;
            if (n < NANCH) {
                float p = expf(pl[n] - rm[n]) / rs[n];
                flag = (p <= SCORE_TH);
            }
            u64 bal = __ballot(flag);
            u64 below = (lane == 0) ? 0ull : (~0ull >> (64 - lane));
            int excl = (int)__popcll(bal & below);
            if (flag && (fillcnt + excl) < need)
                cand[gathered + fillcnt + excl] =
                    (u64)(0xFFFFFFFFu - (unsigned)n);
            fillcnt += (int)__popcll(bal);
        }
        __syncthreads();
        r0 = cand[lane]; r1 = cand[64 + lane];
        r2 = cand[128 + lane]; r3 = cand[192 + lane];
    }

    // ---- decode boxes/areas per slot; publish to LDS for broadcast ----
    float4 b0, b1, b2, b3;
    float a0, a1, a2, a3, v0f, v1f, v2f, v3f;
    {
#pragma clang fp contract(off)
        const float4* lt4 = reinterpret_cast<const float4*>(ltrb)
                            + (size_t)b * NANCH;
        unsigned n0_ = 0xFFFFFFFFu - (unsigned)(r0 & 0xFFFFFFFFull);
        unsigned n1_ = 0xFFFFFFFFu - (unsigned)(r1 & 0xFFFFFFFFull);
        unsigned n2_ = 0xFFFFFFFFu - (unsigned)(r2 & 0xFFFFFFFFull);
        v0f = __uint_as_float((unsigned)(r0 >> 32));
        v1f = __uint_as_float((unsigned)(r1 >> 32));
        v2f = __uint_as_float((unsigned)(r2 >> 32));
        b0 = lt4[n0_]; b1 = lt4[n1_]; b2 = lt4[n2_];
        a0 = (b0.z - b0.x) * (b0.w - b0.y);
        a1 = (b1.z - b1.x) * (b1.w - b1.y);
        a2 = (b2.z - b2.x) * (b2.w - b2.y);
        box4[lane] = b0;        areas[lane] = a0;
        box4[64 + lane] = b1;   areas[64 + lane] = a1;
        box4[128 + lane] = b2;  areas[128 + lane] = a2;
        if (lane < MAXO - 192) {
            unsigned n3_ = 0xFFFFFFFFu - (unsigned)(r3 & 0xFFFFFFFFull);
            v3f = __uint_as_float((unsigned)(r3 >> 32));
            b3 = lt4[n3_];
            a3 = (b3.z - b3.x) * (b3.w - b3.y);
            box4[192 + lane] = b3;  areas[192 + lane] = a3;
        } else {
            v3f = 0.f; b3 = make_float4(0.f, 0.f, 0.f, 0.f); a3 = 0.f;
        }
    }
    const bool j3v = (lane < MAXO - 192);
    const u64 vm0 = __ballot(v0f > 0.f);
    const u64 vm1 = __ballot(v1f > 0.f);
    const u64 vm2 = __ballot(v2f > 0.f);
    const u64 vm3 = __ballot(j3v && (v3f > 0.f));
    __syncthreads();

    // Lazy greedy NMS, single wave, zero barriers. Exact reference recurrence.
    u64 k0 = ~0ull, k1 = ~0ull, k2 = ~0ull, k3 = ~0ull;
    {
#pragma clang fp contract(off)
        int i;
        {
            u64 c; i = -1;
            if ((c = k0 & vm0))      i = __builtin_ctzll(c);
            else if ((c = k1 & vm1)) i = 64 + __builtin_ctzll(c);
            else if ((c = k2 & vm2)) i = 128 + __builtin_ctzll(c);
            else if ((c = k3 & vm3)) i = 192 + __builtin_ctzll(c);
        }
        while (i >= 0) {
            const float4 bi = box4[i];     // broadcast LDS read
            const float ai = areas[i];     // broadcast LDS read
            float l0 = fmaxf(bi.x, b0.x), t0 = fmaxf(bi.y, b0.y);
            float r0_ = fminf(bi.z, b0.z), d0 = fminf(bi.w, b0.w);
            float in0 = fmaxf(r0_ - l0, 0.f) * fmaxf(d0 - t0, 0.f);
            bool s0p = (in0 / (ai + a0 - in0 + 1e-12f)) >= IOU_TH;
            float l1 = fmaxf(bi.x, b1.x), t1 = fmaxf(bi.y, b1.y);
            float r1_ = fminf(bi.z, b1.z), d1 = fminf(bi.w, b1.w);
            float in1 = fmaxf(r1_ - l1, 0.f) * fmaxf(d1 - t1, 0.f);
            bool s1p = (in1 / (ai + a1 - in1 + 1e-12f)) >= IOU_TH;
            float l2 = fmaxf(bi.x, b2.x), t2_ = fmaxf(bi.y, b2.y);
            float r2_ = fminf(bi.z, b2.z), d2 = fminf(bi.w, b2.w);
            float in2 = fmaxf(r2_ - l2, 0.f) * fmaxf(d2 - t2_, 0.f);
            bool s2p = (in2 / (ai + a2 - in2 + 1e-12f)) >= IOU_TH;
            float l3 = fmaxf(bi.x, b3.x), t3 = fmaxf(bi.y, b3.y);
            float r3_ = fminf(bi.z, b3.z), d3 = fminf(bi.w, b3.w);
            float in3 = fmaxf(r3_ - l3, 0.f) * fmaxf(d3 - t3, 0.f);
            bool s3p = (in3 / (ai + a3 - in3 + 1e-12f)) >= IOU_TH;

            u64 s0 = __ballot(s0p && (lane > i));
            u64 s1 = __ballot(s1p && (64 + lane > i));
            u64 s2 = __ballot(s2p && (128 + lane > i));
            u64 s3 = __ballot(s3p && j3v && (192 + lane > i));
            k0 &= ~s0; k1 &= ~s1; k2 &= ~s2; k3 &= ~s3;

            int w = i >> 6, bit = i & 63;
            u64 above = (bit == 63) ? 0ull : (~0ull << (bit + 1));
            u64 cur = ((w == 0) ? (k0 & vm0) : (w == 1) ? (k1 & vm1)
                       : (w == 2) ? (k2 & vm2) : (k3 & vm3)) & above;
            i = -1;
            while (true) {
                if (cur) { i = w * 64 + __builtin_ctzll(cur); break; }
                if (++w >= 4) break;
                cur = (w == 1) ? (k1 & vm1) : (w == 2) ? (k2 & vm2)
                                            : (k3 & vm3);
            }
        }
    }

    // ---- outputs ----
    {
        float* pv  = pcVals + (size_t)bc * MAXO;
        float4* pb4 = reinterpret_cast<float4*>(pcBoxes + (size_t)bc * MAXO * 4);
        bool kp0 = (k0 >> lane) & 1ull, kp1 = (k1 >> lane) & 1ull;
        bool kp2 = (k2 >> lane) & 1ull, kp3 = (k3 >> lane) & 1ull;
        pv[lane]        = (kp0 && v0f > 0.f) ? v0f : 0.f;
        pv[64 + lane]   = (kp1 && v1f > 0.f) ? v1f : 0.f;
        pv[128 + lane]  = (kp2 && v2f > 0.f) ? v2f : 0.f;
        pb4[lane] = b0; pb4[64 + lane] = b1; pb4[128 + lane] = b2;
        if (j3v) {
            pv[192 + lane] = (kp3 && v3f > 0.f) ? v3f : 0.f;
            pb4[192 + lane] = b3;
        }
    }

    // Compact kept keys into per-image list (ballot-ranked, no atom. races).
    {
        u64 km0 = k0 & vm0, km1 = k1 & vm1, km2 = k2 & vm2, km3 = k3 & vm3;
        int c0 = (int)__popcll(km0), c1 = (int)__popcll(km1);
        int c2 = (int)__popcll(km2), c3 = (int)__popcll(km3);
        int tot = c0 + c1 + c2 + c3;
        int kb = 0;
        if (lane == 0 && tot > 0) kb = atomicAdd(&imgcnt[b], tot);
        kb = __shfl(kb, 0);
        u64 below = (lane == 0) ? 0ull : (~0ull >> (64 - lane));
        u64* dst = imglist + (size_t)b * IMGCAP + kb;
        const u64 himask = 0xFFFFFFFF00000000ull;
        if ((km0 >> lane) & 1ull) {
            unsigned g = (unsigned)((cls - 1) * MAXO + lane);
            dst[__popcll(km0 & below)] =
                (r0 & himask) | (u64)(0xFFFFFFFFu - g);
        }
        if ((km1 >> lane) & 1ull) {
            unsigned g = (unsigned)((cls - 1) * MAXO + 64 + lane);
            dst[c0 + __popcll(km1 & below)] =
                (r1 & himask) | (u64)(0xFFFFFFFFu - g);
        }
        if ((km2 >> lane) & 1ull) {
            unsigned g = (unsigned)((cls - 1) * MAXO + 128 + lane);
            dst[c0 + c1 + __popcll(km2 & below)] =
                (r2 & himask) | (u64)(0xFFFFFFFFu - g);
        }
        if ((km3 >> lane) & 1ull) {
            unsigned g = (unsigned)((cls - 1) * MAXO + 192 + lane);
            dst[c0 + c1 + c2 + __popcll(km3 & below)] =
                (r3 & himask) | (u64)(0xFFFFFFFFu - g);
        }
    }
}

// Kernel 3: per image, exact top-200. Live path reads the compact kept list
// (~2-4k entries); dense fallback (NZ<200) kept verbatim.
__global__ __launch_bounds__(256) void ssd_final_topk(
    const float* __restrict__ pcVals, const float* __restrict__ pcBoxes,
    const int* __restrict__ imgcnt, const u64* __restrict__ imglist,
    float* __restrict__ out) {
    __shared__ unsigned int hist[NBIN];
    __shared__ u64 cand[CAP];
    __shared__ int wtot[4];
    __shared__ int cnt, cutbin, nztot;

    const int tid  = threadIdx.x;
    const int lane = tid & 63;
    const int wv   = tid >> 6;
    const int b    = blockIdx.x;
    const int TOT  = C1 * MAXO;   // 16000
    const float* pv = pcVals + (size_t)b * TOT;
    const int NZ   = imgcnt[b];

    for (int i = tid; i < NBIN; i += 256) hist[i] = 0u;
    if (tid == 0) { cnt = 0; cutbin = 1; }
    __syncthreads();

    int count;
    if (NZ >= MAXO) {
        const u64* lst = imglist + (size_t)b * IMGCAP;
        for (int i = tid; i < NZ; i += 256) {
            unsigned bits = (unsigned)(lst[i] >> 32);
            unsigned bin = ((bits - BINBASE) >> 15) + 1u;
            if (bin > NBIN - 1) bin = NBIN - 1;
            atomicAdd(&hist[bin], 1u);
        }
        __syncthreads();

        const int base = tid * 8;
        int loc = 0;
        for (int k = 0; k < 8; ++k) loc += (int)hist[base + k];
        int sfx = loc;
        for (int off = 1; off < 64; off <<= 1) {
            int t = __shfl_down(sfx, off, 64);
            if (lane + off < 64) sfx += t;
        }
        if (lane == 0) wtot[wv] = sfx;
        __syncthreads();
        int crossSuf = 0;
        for (int w2 = wv + 1; w2 < 4; ++w2) crossSuf += wtot[w2];
        {
            int S = (sfx - loc) + crossSuf;
            for (int k = 7; k >= 0; --k) {
                int binv = (int)hist[base + k];
                int Sk = S + binv;
                int bin = base + k;
                if (bin >= 1 && Sk >= MAXO && S < MAXO) cutbin = bin;
                S = Sk;
            }
        }
        __syncthreads();
        const int B = cutbin;

        for (int i = tid; i < NZ; i += 256) {
            u64 k = lst[i];
            unsigned bits = (unsigned)(k >> 32);
            unsigned bin = ((bits - BINBASE) >> 15) + 1u;
            if (bin > NBIN - 1) bin = NBIN - 1;
            if ((int)bin >= B) {
                int pos = atomicAdd(&cnt, 1);
                if (pos < CAP) cand[pos] = k;
            }
        }
        __syncthreads();
        count = min(cnt, CAP);
    } else {
        // Dense fallback (dead in practice).
        for (int g = tid; g < TOT; g += 256) {
            float v = pv[g];
            if (v > 0.f) {
                unsigned bits = __float_as_uint(v);
                unsigned bin = ((bits - BINBASE) >> 15) + 1u;
                if (bin > NBIN - 1) bin = NBIN - 1;
                atomicAdd(&hist[bin], 1u);
            }
        }
        __syncthreads();
        const int base = tid * 8;
        int loc = 0;
        for (int k = 0; k < 8; ++k) loc += (int)hist[base + k];
        int sfx = loc;
        for (int off = 1; off < 64; off <<= 1) {
            int t = __shfl_down(sfx, off, 64);
            if (lane + off < 64) sfx += t;
        }
        if (lane == 0) wtot[wv] = sfx;
        __syncthreads();
        int crossSuf = 0;
        for (int w2 = wv + 1; w2 < 4; ++w2) crossSuf += wtot[w2];
        if (tid == 0) nztot = wtot[0] + wtot[1] + wtot[2] + wtot[3];
        {
            int S = (sfx - loc) + crossSuf;
            for (int k = 7; k >= 0; --k) {
                int binv = (int)hist[base + k];
                int Sk = S + binv;
                int bin = base + k;
                if (bin >= 1 && Sk >= MAXO && S < MAXO) cutbin = bin;
                S = Sk;
            }
        }
        __syncthreads();
        int B = (nztot >= MAXO) ? cutbin : 1;

        for (int g = tid; g < TOT; g += 256) {
            float v = pv[g];
            if (v > 0.f) {
                unsigned bits = __float_as_uint(v);
                unsigned bin = ((bits - BINBASE) >> 15) + 1u;
                if (bin > NBIN - 1) bin = NBIN - 1;
                if ((int)bin >= B) {
                    int pos = atomicAdd(&cnt, 1);
                    if (pos < CAP)
                        cand[pos] = ((u64)bits << 32)
                                  | (u64)(0xFFFFFFFFu - (unsigned)g);
                }
            }
        }
        __syncthreads();
        count = min(cnt, CAP);

        if (count < MAXO) {   // zero-fill, smallest flat index first
            if (tid == 0) {
                int c = count;
                for (int g = 0; g < TOT && c < MAXO; ++g) {
                    if (!(pv[g] > 0.f)) {
                        cand[c++] = (u64)(0xFFFFFFFFu - (unsigned)g);
                    }
                }
                cnt = c;
            }
            __syncthreads();
            count = min(cnt, CAP);
        }
    }

    u64 key;
    if (count <= 256) {
        key = (tid < count) ? cand[tid] : 0ull;
        key = regsort256(key, cand, tid);
    } else {
        int P = 256; while (P < count) P <<= 1;
        for (int i = count + tid; i < P; i += 256) cand[i] = 0ull;
        __syncthreads();
        bitonic_desc(cand, P, tid, 256);
        key = cand[tid];
    }

    if (tid < MAXO) {
        float sc      = __uint_as_float((unsigned)(key >> 32));
        unsigned flat = 0xFFFFFFFFu - (unsigned)(key & 0xFFFFFFFFull);
        int cls = (int)(flat / MAXO) + 1;
        const float4 bb =
            reinterpret_cast<const float4*>(pcBoxes)[(size_t)b * TOT + flat];
        reinterpret_cast<float4*>(out)[(size_t)b * MAXO + tid] = bb;
        out[(size_t)BATCH * MAXO * 4 + (size_t)b * MAXO + tid] = (float)cls;
        out[(size_t)BATCH * MAXO * 5 + (size_t)b * MAXO + tid] = sc;
    }
}

extern "C" void kernel_launch(void* const* d_in, const int* in_sizes, int n_in,
                              void* d_out, int out_size, void* d_ws,
                              size_t ws_size, hipStream_t stream) {
    const float* ploc   = (const float*)d_in[0];
    const float* plabel = (const float*)d_in[1];
    const float* dboxes = (const float*)d_in[2];
    float* out = (float*)d_out;

    float* ws      = (float*)d_ws;
    float* ltrb    = ws;                                   // B*N*4
    float* rowmax  = ltrb   + (size_t)BATCH * NANCH * 4;   // B*N
    float* rowsum  = rowmax + (size_t)BATCH * NANCH;       // B*N
    float* pcVals  = rowsum + (size_t)BATCH * NANCH;       // B*80*200
    float* pcBoxes = pcVals + (size_t)BATCH * C1 * MAXO;   // B*80*200*4
    int*   cntg    = (int*)(pcBoxes + (size_t)BATCH * C1 * MAXO * 4);
    int*   imgcnt  = cntg + BATCH * C1;                    // B ints
    char*  after   = (char*)(imgcnt + BATCH);
    u64* bucket = (u64*)(after + ((16 - (((size_t)after) & 15)) & 15));
    u64* imglist = bucket + (size_t)BATCH * C1 * CAPB;     // B * 16000 u64

    hipMemsetAsync(cntg, 0, (size_t)(BATCH * C1 + BATCH) * sizeof(int), stream);
    ssd_decode_stats<<<BATCH * NBLKA, APB, 0, stream>>>(
        ploc, plabel, dboxes, ltrb, rowmax, rowsum, cntg, bucket);
    ssd_class_nms<<<BATCH * C1, 64, 0, stream>>>(
        plabel, rowmax, rowsum, ltrb, cntg, bucket, pcVals, pcBoxes,
        imgcnt, imglist);
    ssd_final_topk<<<BATCH, 256, 0, stream>>>(
        pcVals, pcBoxes, imgcnt, imglist, out);
}

// Round 15
// 223.759 us; speedup vs baseline: 1.3563x; 1.0953x over previous
//
#include <hip/hip_runtime.h>
#include <math.h>

namespace {
constexpr int BATCH = 32;
constexpr int NANCH = 15130;
constexpr int NCLS  = 81;
constexpr int C1    = 80;          // foreground classes
constexpr int MAXO  = 200;
constexpr int APB   = 256;         // anchors per K1 block (= threads)
constexpr int NBLKA = (NANCH + APB - 1) / APB;   // 60
constexpr int CAPK2 = 512;         // K2 cand capacity (live path uses <=256)
constexpr int CAP   = 1024;        // K3 cand capacity
constexpr int CAPB  = 768;         // global bucket capacity (mean 434, sigma 20.5)
constexpr int NBIN  = 2048;        // histogram bins for K3 select
constexpr int NBINK2 = 768;        // K2 bins (shift 16); max used bin 641
constexpr unsigned BINBASE = 0x3D000000u;  // 0.03125f — below any score > 0.05
constexpr int IMGCAP = C1 * MAXO;  // 16000 — worst-case kept per image
}

#define SCORE_TH 0.05f
#define IOU_TH   0.5f

typedef unsigned long long u64;

__device__ __forceinline__ u64 shflx64(u64 v, int mask) {
    int lo = __shfl_xor((int)(unsigned)(v & 0xffffffffull), mask, 64);
    int hi = __shfl_xor((int)(unsigned)(v >> 32), mask, 64);
    return ((u64)(unsigned)hi << 32) | (unsigned)lo;
}

// Descending bitonic sort of P (power of 2) u64 keys in LDS (fallback path).
// Key = (float_bits(score) << 32) | (0xFFFFFFFF - index)
// => order: score desc, then index asc (matches jax.lax.top_k stability).
__device__ __forceinline__ void bitonic_desc(u64* keys, int P,
                                             int tid, int nthr) {
    for (int k = 2; k <= P; k <<= 1) {
        for (int j = k >> 1; j > 0; j >>= 1) {
            for (int i = tid; i < P; i += nthr) {
                int ixj = i ^ j;
                if (ixj > i) {
                    u64 a = keys[i], c = keys[ixj];
                    bool up = ((i & k) == 0);
                    if (up ? (a < c) : (a > c)) { keys[i] = c; keys[ixj] = a; }
                }
            }
            __syncthreads();
        }
    }
}

// Register bitonic sort of 256 keys (one per thread, 256-thread blocks).
// Used by K3. j<64 via shuffles; j in {64,128} via LDS round-trip.
__device__ __forceinline__ u64 regsort256(u64 key, u64* lds, int tid) {
    for (int k = 2; k <= 256; k <<= 1) {
        for (int j = k >> 1; j > 0; j >>= 1) {
            u64 pv;
            if (j < 64) {
                pv = shflx64(key, j);
            } else {
                lds[tid] = key;
                __syncthreads();
                pv = lds[tid ^ j];
            }
            bool up = ((tid & k) == 0);
            bool lt = ((tid & j) == 0);
            u64 mx = (key > pv) ? key : pv;
            u64 mn = (key > pv) ? pv : key;
            key = (up == lt) ? mx : mn;
            if (j >= 64) __syncthreads();
        }
    }
    return key;
}

// Exact reference IoU>=TH predicate (row box bi/ai vs column box bb/aa).
__device__ __forceinline__ bool iou_sup(const float4 bb, const float aa,
                                        const float4 bi, const float ai) {
#pragma clang fp contract(off)
    float l = fmaxf(bi.x, bb.x);
    float t = fmaxf(bi.y, bb.y);
    float r = fminf(bi.z, bb.z);
    float d = fminf(bi.w, bb.w);
    float in_ = fmaxf(r - l, 0.f) * fmaxf(d - t, 0.f);
    return (in_ / (ai + aa - in_ + 1e-12f)) >= IOU_TH;
}

// Kernel 1: one thread per anchor, 81 logits in registers. Exact reference
// op order throughout.
__global__ __launch_bounds__(256, 3) void ssd_decode_stats(
    const float* __restrict__ ploc, const float* __restrict__ plabel,
    const float* __restrict__ dboxes,
    float* __restrict__ ltrb, float* __restrict__ rowmax,
    float* __restrict__ rowsum,
    int* __restrict__ cntg, u64* __restrict__ bucket) {
#pragma clang fp contract(off)
    __shared__ int lcnt[C1], lbase[C1], lrank[C1];

    const int tid = threadIdx.x;
    const int b   = blockIdx.x / NBLKA;
    const int n0  = (blockIdx.x % NBLKA) * APB;
    const int n   = n0 + tid;
    const bool act = (n < NANCH);

    if (tid < C1) lcnt[tid] = 0;

    float x[NCLS];
    if (act) {
        const float* pl = ploc + (size_t)b * 4 * NANCH + n;
        float px = pl[0], py = pl[NANCH], pw = pl[2 * NANCH],
              ph = pl[3 * NANCH];
        float4 db = reinterpret_cast<const float4*>(dboxes)[n];
        float cx = px * 0.1f * db.z + db.x;
        float cy = py * 0.1f * db.w + db.y;
        float w  = expf(pw * 0.2f) * db.z;
        float h  = expf(ph * 0.2f) * db.w;
        float4 o;
        o.x = cx - 0.5f * w; o.y = cy - 0.5f * h;
        o.z = cx + 0.5f * w; o.w = cy + 0.5f * h;
        reinterpret_cast<float4*>(ltrb)[(size_t)b * NANCH + n] = o;

        const float* pb = plabel + (size_t)b * NCLS * NANCH + n;
#pragma unroll
        for (int c = 0; c < NCLS; ++c) x[c] = pb[(size_t)c * NANCH];

        float m = -INFINITY;
#pragma unroll
        for (int c = 0; c < NCLS; ++c) m = fmaxf(m, x[c]);
#pragma unroll
        for (int c = 0; c < NCLS; ++c) x[c] = expf(x[c] - m);
        float s = 0.f;
#pragma unroll
        for (int c = 0; c < NCLS; ++c) s += x[c];   // serial, reference order
        rowmax[(size_t)b * NANCH + n] = m;
        rowsum[(size_t)b * NANCH + n] = s;

#pragma unroll
        for (int c = 1; c < NCLS; ++c) {
            x[c] = x[c] / s;   // exact IEEE div = reference value
            if (x[c] > SCORE_TH) atomicAdd(&lcnt[c - 1], 1);
        }
    }
    __syncthreads();

    if (tid < C1) {
        int cn = lcnt[tid];
        lbase[tid] = (cn > 0) ? atomicAdd(&cntg[b * C1 + tid], cn) : 0;
        lrank[tid] = 0;
    }
    __syncthreads();

    if (act) {
#pragma unroll
        for (int c = 1; c < NCLS; ++c) {
            if (x[c] > SCORE_TH) {
                int r = atomicAdd(&lrank[c - 1], 1);
                int pos = lbase[c - 1] + r;
                if (pos < CAPB)
                    bucket[(size_t)(b * C1 + (c - 1)) * CAPB + pos] =
                        ((u64)__float_as_uint(x[c]) << 32)
                        | (u64)(0xFFFFFFFFu - (unsigned)n);
            }
        }
    }
}

// Kernel 2: ONE WAVE per (b, class). Histogram-select, in-register bitonic
// sort, then: dense PIPELINED suppression matrix (independent row
// iterations, stored to LDS only when nonzero) + SPARSE propagation over
// nonzero rows (zero rows are provable no-ops in the reference recurrence).
__global__ __launch_bounds__(64) void ssd_class_nms(
    const float* __restrict__ plabel, const float* __restrict__ rowmax,
    const float* __restrict__ rowsum, const float* __restrict__ ltrb,
    const int* __restrict__ cntg, const u64* __restrict__ bucket,
    float* __restrict__ pcVals, float* __restrict__ pcBoxes,
    int* __restrict__ imgcnt, u64* __restrict__ imglist) {
    __shared__ u64 cand[CAPK2];               // 4 KB
    __shared__ u64 pool[MAXO * 4];            // 6.4 KB: hist, then supflat
    __shared__ float4 box4[MAXO];             // 3.2 KB
    __shared__ float areas[MAXO];             // 0.8 KB
    __shared__ int cnt, cutbin;

    unsigned* hist = (unsigned*)pool;         // select phase alias (3 KB)

    const int lane = threadIdx.x;             // 0..63, one wave
    const int b    = blockIdx.x / C1;
    const int cls  = blockIdx.x % C1 + 1;     // skip background
    const int bc   = b * C1 + (cls - 1);

    for (int i = lane; i < NBINK2; i += 64) hist[i] = 0u;
    if (lane == 0) { cnt = 0; cutbin = 1; }
    __syncthreads();

    const float* pl = plabel + ((size_t)b * NCLS + cls) * NANCH;
    const float* rm = rowmax + (size_t)b * NANCH;
    const float* rs = rowsum + (size_t)b * NANCH;
    const u64* bkt = bucket + (size_t)bc * CAPB;

    const int gcount = cntg[bc];
    const bool ovf = (gcount > CAPB);   // uniform; dead in practice
    int gathered;

    if (!ovf) {
        // Pass 1: histogram (bin = ((bits-BINBASE)>>16)+1, monotone in value).
        for (int i = lane; i < gcount; i += 64) {
            unsigned bits = (unsigned)(bkt[i] >> 32);
            unsigned bin = ((bits - BINBASE) >> 16) + 1u;
            if (bin > NBINK2 - 1) bin = NBINK2 - 1;
            atomicAdd(&hist[bin], 1u);
        }
        __syncthreads();

        // Lane owns 12 bins; wave suffix-scan via shfl_down.
        const int base = lane * 12;
        int loc = 0;
#pragma unroll
        for (int k = 0; k < 12; ++k) loc += (int)hist[base + k];
        int sfx = loc;
        for (int off = 1; off < 64; off <<= 1) {
            int t = __shfl_down(sfx, off, 64);
            if (lane + off < 64) sfx += t;
        }
        const int nztot = __shfl(sfx, 0);
        {
            int S = sfx - loc;   // suffix strictly beyond my 12-bin group
            for (int k = 11; k >= 0; --k) {
                int binv = (int)hist[base + k];
                int Sk = S + binv;
                int bin = base + k;
                if (bin >= 1 && Sk >= MAXO && S < MAXO) cutbin = bin;
                S = Sk;
            }
        }
        __syncthreads();
        const int B = (nztot >= MAXO) ? cutbin : 1;

        // Pass 2: gather keys with bin >= B (top-200 subset; ~205 items).
        for (int i = lane; i < gcount; i += 64) {
            u64 k = bkt[i];
            unsigned bits = (unsigned)(k >> 32);
            unsigned bin = ((bits - BINBASE) >> 16) + 1u;
            if (bin > NBINK2 - 1) bin = NBINK2 - 1;
            if ((int)bin >= B) {
                int pos = atomicAdd(&cnt, 1);
                if (pos < CAPK2) cand[pos] = k;
            }
        }
        __syncthreads();
        gathered = min(cnt, CAPK2);
    } else {
        // Overflow fallback (dead): full rescan, no select.
        for (int n = lane; n < NANCH; n += 64) {
            float p = expf(pl[n] - rm[n]) / rs[n];
            if (p > SCORE_TH) {
                int pos = atomicAdd(&cnt, 1);
                if (pos < CAPK2)
                    cand[pos] = ((u64)__float_as_uint(p) << 32)
                              | (u64)(0xFFFFFFFFu - (unsigned)n);
            }
        }
        __syncthreads();
        gathered = min(cnt, CAPK2);
    }

    // ---- sort: element e = s*64 + lane lives in register r_s of lane ----
    u64 r0, r1, r2, r3;
    if (gathered <= 256) {
        r0 = (lane < gathered) ? cand[lane] : 0ull;
        r1 = (64 + lane < gathered) ? cand[64 + lane] : 0ull;
        r2 = (128 + lane < gathered) ? cand[128 + lane] : 0ull;
        r3 = (192 + lane < gathered) ? cand[192 + lane] : 0ull;

        auto SH = [&](u64& rr, int j, bool up) {
            u64 pv = shflx64(rr, j);
            bool lt = ((lane & j) == 0);
            u64 mx = (rr > pv) ? rr : pv;
            u64 mn = (rr > pv) ? pv : rr;
            rr = (up == lt) ? mx : mn;
        };
        auto CE = [](u64& a, u64& c, bool up) {   // a = smaller index
            u64 mx = (a > c) ? a : c;
            u64 mn = (a > c) ? c : a;
            a = up ? mx : mn;
            c = up ? mn : mx;
        };
        for (int k = 2; k <= 32; k <<= 1) {
            for (int j = k >> 1; j > 0; j >>= 1) {
                bool up = ((lane & k) == 0);
                SH(r0, j, up); SH(r1, j, up); SH(r2, j, up); SH(r3, j, up);
            }
        }
        for (int j = 32; j > 0; j >>= 1) {
            SH(r0, j, true); SH(r1, j, false); SH(r2, j, true); SH(r3, j, false);
        }
        CE(r0, r1, true); CE(r2, r3, false);
        for (int j = 32; j > 0; j >>= 1) {
            SH(r0, j, true); SH(r1, j, true); SH(r2, j, false); SH(r3, j, false);
        }
        CE(r0, r2, true); CE(r1, r3, true);
        CE(r0, r1, true); CE(r2, r3, true);
        for (int j = 32; j > 0; j >>= 1) {
            SH(r0, j, true); SH(r1, j, true); SH(r2, j, true); SH(r3, j, true);
        }
    } else {
        // Fallback (dead): LDS bitonic over 512.
        for (int i = gathered + lane; i < CAPK2; i += 64) cand[i] = 0ull;
        __syncthreads();
        bitonic_desc(cand, CAPK2, lane, 64);
        r0 = cand[lane]; r1 = cand[64 + lane];
        r2 = cand[128 + lane]; r3 = cand[192 + lane];
    }

    // <200 positives: fill with smallest anchor idx (top_k zero tie-break). Dead.
    if (gathered < MAXO) {
        cand[lane] = r0; cand[64 + lane] = r1;
        cand[128 + lane] = r2; cand[192 + lane] = r3;
        __syncthreads();
        const int need = MAXO - gathered;
        int fillcnt = 0;   // wave-uniform
        for (int base2 = 0; base2 < NANCH && fillcnt < need; base2 += 64) {
            int n = base2 + lane;
            bool flag = false;
            if (n < NANCH) {
                float p = expf(pl[n] - rm[n]) / rs[n];
                flag = (p <= SCORE_TH);
            }
            u64 bal = __ballot(flag);
            u64 below = (lane == 0) ? 0ull : (~0ull >> (64 - lane));
            int excl = (int)__popcll(bal & below);
            if (flag && (fillcnt + excl) < need)
                cand[gathered + fillcnt + excl] =
                    (u64)(0xFFFFFFFFu - (unsigned)n);
            fillcnt += (int)__popcll(bal);
        }
        __syncthreads();
        r0 = cand[lane]; r1 = cand[64 + lane];
        r2 = cand[128 + lane]; r3 = cand[192 + lane];
    }

    // ---- decode boxes/areas per slot; publish to LDS for broadcast ----
    float4 b0, b1, b2, b3;
    float a0, a1, a2, a3, v0f, v1f, v2f, v3f;
    {
#pragma clang fp contract(off)
        const float4* lt4 = reinterpret_cast<const float4*>(ltrb)
                            + (size_t)b * NANCH;
        unsigned n0_ = 0xFFFFFFFFu - (unsigned)(r0 & 0xFFFFFFFFull);
        unsigned n1_ = 0xFFFFFFFFu - (unsigned)(r1 & 0xFFFFFFFFull);
        unsigned n2_ = 0xFFFFFFFFu - (unsigned)(r2 & 0xFFFFFFFFull);
        v0f = __uint_as_float((unsigned)(r0 >> 32));
        v1f = __uint_as_float((unsigned)(r1 >> 32));
        v2f = __uint_as_float((unsigned)(r2 >> 32));
        b0 = lt4[n0_]; b1 = lt4[n1_]; b2 = lt4[n2_];
        a0 = (b0.z - b0.x) * (b0.w - b0.y);
        a1 = (b1.z - b1.x) * (b1.w - b1.y);
        a2 = (b2.z - b2.x) * (b2.w - b2.y);
        box4[lane] = b0;        areas[lane] = a0;
        box4[64 + lane] = b1;   areas[64 + lane] = a1;
        box4[128 + lane] = b2;  areas[128 + lane] = a2;
        if (lane < MAXO - 192) {
            unsigned n3_ = 0xFFFFFFFFu - (unsigned)(r3 & 0xFFFFFFFFull);
            v3f = __uint_as_float((unsigned)(r3 >> 32));
            b3 = lt4[n3_];
            a3 = (b3.z - b3.x) * (b3.w - b3.y);
            box4[192 + lane] = b3;  areas[192 + lane] = a3;
        } else {
            v3f = 0.f; b3 = make_float4(0.f, 0.f, 0.f, 0.f); a3 = 0.f;
        }
    }
    const bool j3v = (lane < MAXO - 192);
    const u64 vm0 = __ballot(v0f > 0.f);
    const u64 vm1 = __ballot(v1f > 0.f);
    const u64 vm2 = __ballot(v2f > 0.f);
    const u64 vm3 = __ballot(j3v && (v3f > 0.f));
    __syncthreads();   // box4/areas ready; hist no longer needed -> supflat

    u64* supflat = pool;   // NMS phase alias (rows stored only if nonzero)

    // ---- dense suppression matrix: independent row iterations (pipelined),
    //      word-triangular (row block w computes slots >= w only) ----
    u64 nz0 = 0, nz1 = 0, nz2 = 0, nz3 = 0;
    for (int i = 0; i < 64; ++i) {
        float4 bi = box4[i]; float ai = areas[i];
        u64 s0 = __ballot(iou_sup(b0, a0, bi, ai) && (lane > i));
        u64 s1 = __ballot(iou_sup(b1, a1, bi, ai));
        u64 s2 = __ballot(iou_sup(b2, a2, bi, ai));
        u64 s3 = __ballot(iou_sup(b3, a3, bi, ai) && j3v);
        if ((s0 | s1 | s2 | s3) != 0ull) {
            nz0 |= 1ull << i;
            if (lane == 0) {
                supflat[i * 4 + 0] = s0; supflat[i * 4 + 1] = s1;
                supflat[i * 4 + 2] = s2; supflat[i * 4 + 3] = s3;
            }
        }
    }
    for (int i = 64; i < 128; ++i) {
        float4 bi = box4[i]; float ai = areas[i];
        u64 s1 = __ballot(iou_sup(b1, a1, bi, ai) && (64 + lane > i));
        u64 s2 = __ballot(iou_sup(b2, a2, bi, ai));
        u64 s3 = __ballot(iou_sup(b3, a3, bi, ai) && j3v);
        if ((s1 | s2 | s3) != 0ull) {
            nz1 |= 1ull << (i - 64);
            if (lane == 0) {
                supflat[i * 4 + 1] = s1;
                supflat[i * 4 + 2] = s2; supflat[i * 4 + 3] = s3;
            }
        }
    }
    for (int i = 128; i < 192; ++i) {
        float4 bi = box4[i]; float ai = areas[i];
        u64 s2 = __ballot(iou_sup(b2, a2, bi, ai) && (128 + lane > i));
        u64 s3 = __ballot(iou_sup(b3, a3, bi, ai) && j3v);
        if ((s2 | s3) != 0ull) {
            nz2 |= 1ull << (i - 128);
            if (lane == 0) {
                supflat[i * 4 + 2] = s2; supflat[i * 4 + 3] = s3;
            }
        }
    }
    for (int i = 192; i < MAXO; ++i) {
        float4 bi = box4[i]; float ai = areas[i];
        u64 s3 = __ballot(iou_sup(b3, a3, bi, ai) && j3v && (192 + lane > i));
        if (s3 != 0ull) {
            nz3 |= 1ull << (i - 192);
            if (lane == 0) supflat[i * 4 + 3] = s3;
        }
    }
    __syncthreads();   // supflat visible (lane-0 writes -> all lanes read)

    // ---- sparse propagation: iterate keep & vmask & nz in increasing i.
    // Zero rows are no-ops in the reference recurrence; identical result.
    // All lanes execute identically (broadcast LDS reads).
    u64 k0 = ~0ull, k1 = ~0ull, k2 = ~0ull, k3 = ~0ull;
    {
        int i = -1;
        u64 c;
        if ((c = k0 & vm0 & nz0))      i = __builtin_ctzll(c);
        else if ((c = k1 & vm1 & nz1)) i = 64 + __builtin_ctzll(c);
        else if ((c = k2 & vm2 & nz2)) i = 128 + __builtin_ctzll(c);
        else if ((c = k3 & vm3 & nz3)) i = 192 + __builtin_ctzll(c);
        while (i >= 0) {
            int wr = i >> 6, bit = i & 63;
            if (wr == 0) {
                k0 &= ~supflat[i * 4 + 0]; k1 &= ~supflat[i * 4 + 1];
                k2 &= ~supflat[i * 4 + 2]; k3 &= ~supflat[i * 4 + 3];
            } else if (wr == 1) {
                k1 &= ~supflat[i * 4 + 1];
                k2 &= ~supflat[i * 4 + 2]; k3 &= ~supflat[i * 4 + 3];
            } else if (wr == 2) {
                k2 &= ~supflat[i * 4 + 2]; k3 &= ~supflat[i * 4 + 3];
            } else {
                k3 &= ~supflat[i * 4 + 3];
            }
            u64 above = (bit == 63) ? 0ull : (~0ull << (bit + 1));
            u64 cur = ((wr == 0) ? (k0 & vm0 & nz0)
                     : (wr == 1) ? (k1 & vm1 & nz1)
                     : (wr == 2) ? (k2 & vm2 & nz2)
                                 : (k3 & vm3 & nz3)) & above;
            i = -1;
            while (true) {
                if (cur) { i = wr * 64 + __builtin_ctzll(cur); break; }
                if (++wr >= 4) break;
                cur = (wr == 1) ? (k1 & vm1 & nz1)
                    : (wr == 2) ? (k2 & vm2 & nz2) : (k3 & vm3 & nz3);
            }
        }
    }

    // ---- outputs ----
    {
        float* pv  = pcVals + (size_t)bc * MAXO;
        float4* pb4 = reinterpret_cast<float4*>(pcBoxes + (size_t)bc * MAXO * 4);
        bool kp0 = (k0 >> lane) & 1ull, kp1 = (k1 >> lane) & 1ull;
        bool kp2 = (k2 >> lane) & 1ull, kp3 = (k3 >> lane) & 1ull;
        pv[lane]        = (kp0 && v0f > 0.f) ? v0f : 0.f;
        pv[64 + lane]   = (kp1 && v1f > 0.f) ? v1f : 0.f;
        pv[128 + lane]  = (kp2 && v2f > 0.f) ? v2f : 0.f;
        pb4[lane] = b0; pb4[64 + lane] = b1; pb4[128 + lane] = b2;
        if (j3v) {
            pv[192 + lane] = (kp3 && v3f > 0.f) ? v3f : 0.f;
            pb4[192 + lane] = b3;
        }
    }

    // Compact kept keys into per-image list (ballot-ranked).
    {
        u64 km0 = k0 & vm0, km1 = k1 & vm1, km2 = k2 & vm2, km3 = k3 & vm3;
        int c0 = (int)__popcll(km0), c1 = (int)__popcll(km1);
        int c2 = (int)__popcll(km2), c3 = (int)__popcll(km3);
        int tot = c0 + c1 + c2 + c3;
        int kb = 0;
        if (lane == 0 && tot > 0) kb = atomicAdd(&imgcnt[b], tot);
        kb = __shfl(kb, 0);
        u64 below = (lane == 0) ? 0ull : (~0ull >> (64 - lane));
        u64* dst = imglist + (size_t)b * IMGCAP + kb;
        const u64 himask = 0xFFFFFFFF00000000ull;
        if ((km0 >> lane) & 1ull) {
            unsigned g = (unsigned)((cls - 1) * MAXO + lane);
            dst[__popcll(km0 & below)] =
                (r0 & himask) | (u64)(0xFFFFFFFFu - g);
        }
        if ((km1 >> lane) & 1ull) {
            unsigned g = (unsigned)((cls - 1) * MAXO + 64 + lane);
            dst[c0 + __popcll(km1 & below)] =
                (r1 & himask) | (u64)(0xFFFFFFFFu - g);
        }
        if ((km2 >> lane) & 1ull) {
            unsigned g = (unsigned)((cls - 1) * MAXO + 128 + lane);
            dst[c0 + c1 + __popcll(km2 & below)] =
                (r2 & himask) | (u64)(0xFFFFFFFFu - g);
        }
        if ((km3 >> lane) & 1ull) {
            unsigned g = (unsigned)((cls - 1) * MAXO + 192 + lane);
            dst[c0 + c1 + c2 + __popcll(km3 & below)] =
                (r3 & himask) | (u64)(0xFFFFFFFFu - g);
        }
    }
}

// Kernel 3: per image, exact top-200. Live path reads the compact kept list
// (~15k entries); dense fallback (NZ<200) kept verbatim.
__global__ __launch_bounds__(256) void ssd_final_topk(
    const float* __restrict__ pcVals, const float* __restrict__ pcBoxes,
    const int* __restrict__ imgcnt, const u64* __restrict__ imglist,
    float* __restrict__ out) {
    __shared__ unsigned int hist[NBIN];
    __shared__ u64 cand[CAP];
    __shared__ int wtot[4];
    __shared__ int cnt, cutbin, nztot;

    const int tid  = threadIdx.x;
    const int lane = tid & 63;
    const int wv   = tid >> 6;
    const int b    = blockIdx.x;
    const int TOT  = C1 * MAXO;   // 16000
    const float* pv = pcVals + (size_t)b * TOT;
    const int NZ   = imgcnt[b];

    for (int i = tid; i < NBIN; i += 256) hist[i] = 0u;
    if (tid == 0) { cnt = 0; cutbin = 1; }
    __syncthreads();

    int count;
    if (NZ >= MAXO) {
        const u64* lst = imglist + (size_t)b * IMGCAP;
        for (int i = tid; i < NZ; i += 256) {
            unsigned bits = (unsigned)(lst[i] >> 32);
            unsigned bin = ((bits - BINBASE) >> 15) + 1u;
            if (bin > NBIN - 1) bin = NBIN - 1;
            atomicAdd(&hist[bin], 1u);
        }
        __syncthreads();

        const int base = tid * 8;
        int loc = 0;
        for (int k = 0; k < 8; ++k) loc += (int)hist[base + k];
        int sfx = loc;
        for (int off = 1; off < 64; off <<= 1) {
            int t = __shfl_down(sfx, off, 64);
            if (lane + off < 64) sfx += t;
        }
        if (lane == 0) wtot[wv] = sfx;
        __syncthreads();
        int crossSuf = 0;
        for (int w2 = wv + 1; w2 < 4; ++w2) crossSuf += wtot[w2];
        {
            int S = (sfx - loc) + crossSuf;
            for (int k = 7; k >= 0; --k) {
                int binv = (int)hist[base + k];
                int Sk = S + binv;
                int bin = base + k;
                if (bin >= 1 && Sk >= MAXO && S < MAXO) cutbin = bin;
                S = Sk;
            }
        }
        __syncthreads();
        const int B = cutbin;

        for (int i = tid; i < NZ; i += 256) {
            u64 k = lst[i];
            unsigned bits = (unsigned)(k >> 32);
            unsigned bin = ((bits - BINBASE) >> 15) + 1u;
            if (bin > NBIN - 1) bin = NBIN - 1;
            if ((int)bin >= B) {
                int pos = atomicAdd(&cnt, 1);
                if (pos < CAP) cand[pos] = k;
            }
        }
        __syncthreads();
        count = min(cnt, CAP);
    } else {
        // Dense fallback (dead in practice).
        for (int g = tid; g < TOT; g += 256) {
            float v = pv[g];
            if (v > 0.f) {
                unsigned bits = __float_as_uint(v);
                unsigned bin = ((bits - BINBASE) >> 15) + 1u;
                if (bin > NBIN - 1) bin = NBIN - 1;
                atomicAdd(&hist[bin], 1u);
            }
        }
        __syncthreads();
        const int base = tid * 8;
        int loc = 0;
        for (int k = 0; k < 8; ++k) loc += (int)hist[base + k];
        int sfx = loc;
        for (int off = 1; off < 64; off <<= 1) {
            int t = __shfl_down(sfx, off, 64);
            if (lane + off < 64) sfx += t;
        }
        if (lane == 0) wtot[wv] = sfx;
        __syncthreads();
        int crossSuf = 0;
        for (int w2 = wv + 1; w2 < 4; ++w2) crossSuf += wtot[w2];
        if (tid == 0) nztot = wtot[0] + wtot[1] + wtot[2] + wtot[3];
        {
            int S = (sfx - loc) + crossSuf;
            for (int k = 7; k >= 0; --k) {
                int binv = (int)hist[base + k];
                int Sk = S + binv;
                int bin = base + k;
                if (bin >= 1 && Sk >= MAXO && S < MAXO) cutbin = bin;
                S = Sk;
            }
        }
        __syncthreads();
        int B = (nztot >= MAXO) ? cutbin : 1;

        for (int g = tid; g < TOT; g += 256) {
            float v = pv[g];
            if (v > 0.f) {
                unsigned bits = __float_as_uint(v);
                unsigned bin = ((bits - BINBASE) >> 15) + 1u;
                if (bin > NBIN - 1) bin = NBIN - 1;
                if ((int)bin >= B) {
                    int pos = atomicAdd(&cnt, 1);
                    if (pos < CAP)
                        cand[pos] = ((u64)bits << 32)
                                  | (u64)(0xFFFFFFFFu - (unsigned)g);
                }
            }
        }
        __syncthreads();
        count = min(cnt, CAP);

        if (count < MAXO) {   // zero-fill, smallest flat index first
            if (tid == 0) {
                int c = count;
                for (int g = 0; g < TOT && c < MAXO; ++g) {
                    if (!(pv[g] > 0.f)) {
                        cand[c++] = (u64)(0xFFFFFFFFu - (unsigned)g);
                    }
                }
                cnt = c;
            }
            __syncthreads();
            count = min(cnt, CAP);
        }
    }

    u64 key;
    if (count <= 256) {
        key = (tid < count) ? cand[tid] : 0ull;
        key = regsort256(key, cand, tid);
    } else {
        int P = 256; while (P < count) P <<= 1;
        for (int i = count + tid; i < P; i += 256) cand[i] = 0ull;
        __syncthreads();
        bitonic_desc(cand, P, tid, 256);
        key = cand[tid];
    }

    if (tid < MAXO) {
        float sc      = __uint_as_float((unsigned)(key >> 32));
        unsigned flat = 0xFFFFFFFFu - (unsigned)(key & 0xFFFFFFFFull);
        int cls = (int)(flat / MAXO) + 1;
        const float4 bb =
            reinterpret_cast<const float4*>(pcBoxes)[(size_t)b * TOT + flat];
        reinterpret_cast<float4*>(out)[(size_t)b * MAXO + tid] = bb;
        out[(size_t)BATCH * MAXO * 4 + (size_t)b * MAXO + tid] = (float)cls;
        out[(size_t)BATCH * MAXO * 5 + (size_t)b * MAXO + tid] = sc;
    }
}

extern "C" void kernel_launch(void* const* d_in, const int* in_sizes, int n_in,
                              void* d_out, int out_size, void* d_ws,
                              size_t ws_size, hipStream_t stream) {
    const float* ploc   = (const float*)d_in[0];
    const float* plabel = (const float*)d_in[1];
    const float* dboxes = (const float*)d_in[2];
    float* out = (float*)d_out;

    float* ws      = (float*)d_ws;
    float* ltrb    = ws;                                   // B*N*4
    float* rowmax  = ltrb   + (size_t)BATCH * NANCH * 4;   // B*N
    float* rowsum  = rowmax + (size_t)BATCH * NANCH;       // B*N
    float* pcVals  = rowsum + (size_t)BATCH * NANCH;       // B*80*200
    float* pcBoxes = pcVals + (size_t)BATCH * C1 * MAXO;   // B*80*200*4
    int*   cntg    = (int*)(pcBoxes + (size_t)BATCH * C1 * MAXO * 4);
    int*   imgcnt  = cntg + BATCH * C1;                    // B ints
    char*  after   = (char*)(imgcnt + BATCH);
    u64* bucket = (u64*)(after + ((16 - (((size_t)after) & 15)) & 15));
    u64* imglist = bucket + (size_t)BATCH * C1 * CAPB;     // B * 16000 u64

    hipMemsetAsync(cntg, 0, (size_t)(BATCH * C1 + BATCH) * sizeof(int), stream);
    ssd_decode_stats<<<BATCH * NBLKA, APB, 0, stream>>>(
        ploc, plabel, dboxes, ltrb, rowmax, rowsum, cntg, bucket);
    ssd_class_nms<<<BATCH * C1, 64, 0, stream>>>(
        plabel, rowmax, rowsum, ltrb, cntg, bucket, pcVals, pcBoxes,
        imgcnt, imglist);
    ssd_final_topk<<<BATCH, 256, 0, stream>>>(
        pcVals, pcBoxes, imgcnt, imglist, out);
}

// Round 16
// 219.242 us; speedup vs baseline: 1.3843x; 1.0206x over previous
//
#include <hip/hip_runtime.h>
#include <math.h>

namespace {
constexpr int BATCH = 32;
constexpr int NANCH = 15130;
constexpr int NCLS  = 81;
constexpr int C1    = 80;          // foreground classes
constexpr int MAXO  = 200;
constexpr int APB   = 256;         // anchors per K1 block (= threads)
constexpr int NBLKA = (NANCH + APB - 1) / APB;   // 60
constexpr int CAPK2 = 512;         // K2 cand capacity (live path uses <=256)
constexpr int CAP   = 1024;        // K3 cand capacity
constexpr int CAPB  = 768;         // global bucket capacity (mean 434, sigma 20.5)
constexpr int NBIN  = 2048;        // histogram bins for K3 select
constexpr int NBINK2 = 768;        // K2 bins (shift 16); max used bin 641
constexpr unsigned BINBASE = 0x3D000000u;  // 0.03125f — below any score > 0.05
constexpr int IMGCAP = C1 * MAXO;  // 16000 — worst-case kept per image
}

#define SCORE_TH 0.05f
#define IOU_TH   0.5f

typedef unsigned long long u64;

__device__ __forceinline__ u64 shflx64(u64 v, int mask) {
    int lo = __shfl_xor((int)(unsigned)(v & 0xffffffffull), mask, 64);
    int hi = __shfl_xor((int)(unsigned)(v >> 32), mask, 64);
    return ((u64)(unsigned)hi << 32) | (unsigned)lo;
}

// Descending bitonic sort of P (power of 2) u64 keys in LDS (fallback path).
// Key = (float_bits(score) << 32) | (0xFFFFFFFF - index)
// => order: score desc, then index asc (matches jax.lax.top_k stability).
__device__ __forceinline__ void bitonic_desc(u64* keys, int P,
                                             int tid, int nthr) {
    for (int k = 2; k <= P; k <<= 1) {
        for (int j = k >> 1; j > 0; j >>= 1) {
            for (int i = tid; i < P; i += nthr) {
                int ixj = i ^ j;
                if (ixj > i) {
                    u64 a = keys[i], c = keys[ixj];
                    bool up = ((i & k) == 0);
                    if (up ? (a < c) : (a > c)) { keys[i] = c; keys[ixj] = a; }
                }
            }
            __syncthreads();
        }
    }
}

// Register bitonic sort of 256 keys (one per thread, 256-thread blocks).
// Used by K3. j<64 via shuffles; j in {64,128} via LDS round-trip.
__device__ __forceinline__ u64 regsort256(u64 key, u64* lds, int tid) {
    for (int k = 2; k <= 256; k <<= 1) {
        for (int j = k >> 1; j > 0; j >>= 1) {
            u64 pv;
            if (j < 64) {
                pv = shflx64(key, j);
            } else {
                lds[tid] = key;
                __syncthreads();
                pv = lds[tid ^ j];
            }
            bool up = ((tid & k) == 0);
            bool lt = ((tid & j) == 0);
            u64 mx = (key > pv) ? key : pv;
            u64 mn = (key > pv) ? pv : key;
            key = (up == lt) ? mx : mn;
            if (j >= 64) __syncthreads();
        }
    }
    return key;
}

// Exact intersection/denominator parts of the reference IoU expression.
__device__ __forceinline__ void iou_parts(const float4 bb, const float aa,
                                          const float4 bi, const float ai,
                                          float& in_, float& dn) {
#pragma clang fp contract(off)
    float l = fmaxf(bi.x, bb.x);
    float t = fmaxf(bi.y, bb.y);
    float r = fminf(bi.z, bb.z);
    float d = fminf(bi.w, bb.w);
    in_ = fmaxf(r - l, 0.f) * fmaxf(d - t, 0.f);
    dn  = ai + aa - in_ + 1e-12f;
}

// Kernel 1: one thread per anchor, 81 logits in registers. Threshold via
// guard-banded multiply (exact: band -> IEEE div, wave-uniform __any gate);
// exact div computed only for actual candidates.
__global__ __launch_bounds__(256, 3) void ssd_decode_stats(
    const float* __restrict__ ploc, const float* __restrict__ plabel,
    const float* __restrict__ dboxes,
    float* __restrict__ ltrb, float* __restrict__ rowmax,
    float* __restrict__ rowsum,
    int* __restrict__ cntg, u64* __restrict__ bucket) {
#pragma clang fp contract(off)
    __shared__ int lcnt[C1], lbase[C1], lrank[C1];

    const int tid = threadIdx.x;
    const int b   = blockIdx.x / NBLKA;
    const int n0  = (blockIdx.x % NBLKA) * APB;
    const int n   = n0 + tid;
    const bool act = (n < NANCH);

    if (tid < C1) lcnt[tid] = 0;

    float x[NCLS];
    float s = 1.f;
    u64 w0 = 0, w1 = 0;   // pass bits for classes 1..64, 65..80
    if (act) {
        const float* pl = ploc + (size_t)b * 4 * NANCH + n;
        float px = pl[0], py = pl[NANCH], pw = pl[2 * NANCH],
              ph = pl[3 * NANCH];
        float4 db = reinterpret_cast<const float4*>(dboxes)[n];
        float cx = px * 0.1f * db.z + db.x;
        float cy = py * 0.1f * db.w + db.y;
        float w  = expf(pw * 0.2f) * db.z;
        float h  = expf(ph * 0.2f) * db.w;
        float4 o;
        o.x = cx - 0.5f * w; o.y = cy - 0.5f * h;
        o.z = cx + 0.5f * w; o.w = cy + 0.5f * h;
        reinterpret_cast<float4*>(ltrb)[(size_t)b * NANCH + n] = o;

        const float* pb = plabel + (size_t)b * NCLS * NANCH + n;
#pragma unroll
        for (int c = 0; c < NCLS; ++c) x[c] = pb[(size_t)c * NANCH];

        float m = -INFINITY;
#pragma unroll
        for (int c = 0; c < NCLS; ++c) m = fmaxf(m, x[c]);
#pragma unroll
        for (int c = 0; c < NCLS; ++c) x[c] = expf(x[c] - m);
        s = 0.f;
#pragma unroll
        for (int c = 0; c < NCLS; ++c) s += x[c];   // serial, reference order
        rowmax[(size_t)b * NANCH + n] = m;
        rowsum[(size_t)b * NANCH + n] = s;

        // fl(e/s) > 0.05 decided by multiply outside a 2^-21 guard band;
        // band -> exact IEEE div (rounds 8/9 field-verified, absmax 0.0).
        const float sc = s * SCORE_TH;
        const float lo = sc * 0.99999952f;   // (1 - 2^-21)
        const float hi = sc * 1.00000048f;   // (1 + 2^-21)
#pragma unroll
        for (int c = 1; c < NCLS; ++c) {
            float e = x[c];
            bool band = (e >= lo) && (e <= hi);
            bool pass = (e > hi);
            if (__any(band)) pass = band ? ((e / s) > SCORE_TH) : pass;
            if (pass) {
                atomicAdd(&lcnt[c - 1], 1);
                if (c <= 64) w0 |= 1ull << (c - 1);
                else         w1 |= 1ull << (c - 65);
            }
        }
    }
    __syncthreads();

    if (tid < C1) {
        int cn = lcnt[tid];
        lbase[tid] = (cn > 0) ? atomicAdd(&cntg[b * C1 + tid], cn) : 0;
        lrank[tid] = 0;
    }
    __syncthreads();

    if (act) {
#pragma unroll
        for (int c = 1; c < NCLS; ++c) {
            bool pass = (c <= 64) ? ((w0 >> (c - 1)) & 1ull)
                                  : ((w1 >> (c - 65)) & 1ull);
            if (pass) {
                int r = atomicAdd(&lrank[c - 1], 1);
                int pos = lbase[c - 1] + r;
                if (pos < CAPB) {
                    float p = x[c] / s;   // exact IEEE div = reference value
                    bucket[(size_t)(b * C1 + (c - 1)) * CAPB + pos] =
                        ((u64)__float_as_uint(p) << 32)
                        | (u64)(0xFFFFFFFFu - (unsigned)n);
                }
            }
        }
    }
}

// Kernel 2: ONE WAVE per (b, class). Histogram-select, in-register bitonic
// sort, dense pipelined suppression matrix with guard-banded div-free IoU
// (exact; band -> IEEE div), sparse propagation over nonzero rows.
__global__ __launch_bounds__(64) void ssd_class_nms(
    const float* __restrict__ plabel, const float* __restrict__ rowmax,
    const float* __restrict__ rowsum, const float* __restrict__ ltrb,
    const int* __restrict__ cntg, const u64* __restrict__ bucket,
    float* __restrict__ pcVals, float* __restrict__ pcBoxes,
    int* __restrict__ imgcnt, u64* __restrict__ imglist) {
    __shared__ u64 pool[MAXO * 4];              // 6.4 KB: hist, then supflat
    __shared__ __align__(16) u64 candbox[CAPK2];// 4 KB: cand, then box4+areas
    __shared__ int cnt, cutbin;

    unsigned* hist = (unsigned*)pool;           // select-phase alias (3 KB)
    u64* cand = candbox;                        // select/sort/fill alias
    float4* box4 = reinterpret_cast<float4*>(candbox);        // NMS alias
    float* areas = reinterpret_cast<float*>(candbox) + 800;   // bytes 3200..4000

    const int lane = threadIdx.x;             // 0..63, one wave
    const int b    = blockIdx.x / C1;
    const int cls  = blockIdx.x % C1 + 1;     // skip background
    const int bc   = b * C1 + (cls - 1);

    for (int i = lane; i < NBINK2; i += 64) hist[i] = 0u;
    if (lane == 0) { cnt = 0; cutbin = 1; }
    __syncthreads();

    const float* pl = plabel + ((size_t)b * NCLS + cls) * NANCH;
    const float* rm = rowmax + (size_t)b * NANCH;
    const float* rs = rowsum + (size_t)b * NANCH;
    const u64* bkt = bucket + (size_t)bc * CAPB;

    const int gcount = cntg[bc];
    const bool ovf = (gcount > CAPB);   // uniform; dead in practice
    int gathered;

    if (!ovf) {
        // Pass 1: histogram (bin = ((bits-BINBASE)>>16)+1, monotone in value).
        for (int i = lane; i < gcount; i += 64) {
            unsigned bits = (unsigned)(bkt[i] >> 32);
            unsigned bin = ((bits - BINBASE) >> 16) + 1u;
            if (bin > NBINK2 - 1) bin = NBINK2 - 1;
            atomicAdd(&hist[bin], 1u);
        }
        __syncthreads();

        // Lane owns 12 bins; wave suffix-scan via shfl_down.
        const int base = lane * 12;
        int loc = 0;
#pragma unroll
        for (int k = 0; k < 12; ++k) loc += (int)hist[base + k];
        int sfx = loc;
        for (int off = 1; off < 64; off <<= 1) {
            int t = __shfl_down(sfx, off, 64);
            if (lane + off < 64) sfx += t;
        }
        const int nztot = __shfl(sfx, 0);
        {
            int S = sfx - loc;   // suffix strictly beyond my 12-bin group
            for (int k = 11; k >= 0; --k) {
                int binv = (int)hist[base + k];
                int Sk = S + binv;
                int bin = base + k;
                if (bin >= 1 && Sk >= MAXO && S < MAXO) cutbin = bin;
                S = Sk;
            }
        }
        __syncthreads();
        const int B = (nztot >= MAXO) ? cutbin : 1;

        // Pass 2: gather keys with bin >= B (top-200 subset; ~205 items).
        for (int i = lane; i < gcount; i += 64) {
            u64 k = bkt[i];
            unsigned bits = (unsigned)(k >> 32);
            unsigned bin = ((bits - BINBASE) >> 16) + 1u;
            if (bin > NBINK2 - 1) bin = NBINK2 - 1;
            if ((int)bin >= B) {
                int pos = atomicAdd(&cnt, 1);
                if (pos < CAPK2) cand[pos] = k;
            }
        }
        __syncthreads();
        gathered = min(cnt, CAPK2);
    } else {
        // Overflow fallback (dead): full rescan, no select.
        for (int n = lane; n < NANCH; n += 64) {
            float p = expf(pl[n] - rm[n]) / rs[n];
            if (p > SCORE_TH) {
                int pos = atomicAdd(&cnt, 1);
                if (pos < CAPK2)
                    cand[pos] = ((u64)__float_as_uint(p) << 32)
                              | (u64)(0xFFFFFFFFu - (unsigned)n);
            }
        }
        __syncthreads();
        gathered = min(cnt, CAPK2);
    }

    // ---- sort: element e = s*64 + lane lives in register r_s of lane ----
    u64 r0, r1, r2, r3;
    if (gathered <= 256) {
        r0 = (lane < gathered) ? cand[lane] : 0ull;
        r1 = (64 + lane < gathered) ? cand[64 + lane] : 0ull;
        r2 = (128 + lane < gathered) ? cand[128 + lane] : 0ull;
        r3 = (192 + lane < gathered) ? cand[192 + lane] : 0ull;

        auto SH = [&](u64& rr, int j, bool up) {
            u64 pv = shflx64(rr, j);
            bool lt = ((lane & j) == 0);
            u64 mx = (rr > pv) ? rr : pv;
            u64 mn = (rr > pv) ? pv : rr;
            rr = (up == lt) ? mx : mn;
        };
        auto CE = [](u64& a, u64& c, bool up) {   // a = smaller index
            u64 mx = (a > c) ? a : c;
            u64 mn = (a > c) ? c : a;
            a = up ? mx : mn;
            c = up ? mn : mx;
        };
        for (int k = 2; k <= 32; k <<= 1) {
            for (int j = k >> 1; j > 0; j >>= 1) {
                bool up = ((lane & k) == 0);
                SH(r0, j, up); SH(r1, j, up); SH(r2, j, up); SH(r3, j, up);
            }
        }
        for (int j = 32; j > 0; j >>= 1) {
            SH(r0, j, true); SH(r1, j, false); SH(r2, j, true); SH(r3, j, false);
        }
        CE(r0, r1, true); CE(r2, r3, false);
        for (int j = 32; j > 0; j >>= 1) {
            SH(r0, j, true); SH(r1, j, true); SH(r2, j, false); SH(r3, j, false);
        }
        CE(r0, r2, true); CE(r1, r3, true);
        CE(r0, r1, true); CE(r2, r3, true);
        for (int j = 32; j > 0; j >>= 1) {
            SH(r0, j, true); SH(r1, j, true); SH(r2, j, true); SH(r3, j, true);
        }
    } else {
        // Fallback (dead): LDS bitonic over 512.
        for (int i = gathered + lane; i < CAPK2; i += 64) cand[i] = 0ull;
        __syncthreads();
        bitonic_desc(cand, CAPK2, lane, 64);
        r0 = cand[lane]; r1 = cand[64 + lane];
        r2 = cand[128 + lane]; r3 = cand[192 + lane];
    }

    // <200 positives: fill with smallest anchor idx (top_k zero tie-break). Dead.
    if (gathered < MAXO) {
        cand[lane] = r0; cand[64 + lane] = r1;
        cand[128 + lane] = r2; cand[192 + lane] = r3;
        __syncthreads();
        const int need = MAXO - gathered;
        int fillcnt = 0;   // wave-uniform
        for (int base2 = 0; base2 < NANCH && fillcnt < need; base2 += 64) {
            int n = base2 + lane;
            bool flag = false;
            if (n < NANCH) {
                float p = expf(pl[n] - rm[n]) / rs[n];
                flag = (p <= SCORE_TH);
            }
            u64 bal = __ballot(flag);
            u64 below = (lane == 0) ? 0ull : (~0ull >> (64 - lane));
            int excl = (int)__popcll(bal & below);
            if (flag && (fillcnt + excl) < need)
                cand[gathered + fillcnt + excl] =
                    (u64)(0xFFFFFFFFu - (unsigned)n);
            fillcnt += (int)__popcll(bal);
        }
        __syncthreads();
        r0 = cand[lane]; r1 = cand[64 + lane];
        r2 = cand[128 + lane]; r3 = cand[192 + lane];
    }

    // ---- decode boxes/areas per slot; publish to LDS (cand now dead) ----
    float4 b0, b1, b2, b3;
    float a0, a1, a2, a3, v0f, v1f, v2f, v3f;
    {
#pragma clang fp contract(off)
        const float4* lt4 = reinterpret_cast<const float4*>(ltrb)
                            + (size_t)b * NANCH;
        unsigned n0_ = 0xFFFFFFFFu - (unsigned)(r0 & 0xFFFFFFFFull);
        unsigned n1_ = 0xFFFFFFFFu - (unsigned)(r1 & 0xFFFFFFFFull);
        unsigned n2_ = 0xFFFFFFFFu - (unsigned)(r2 & 0xFFFFFFFFull);
        v0f = __uint_as_float((unsigned)(r0 >> 32));
        v1f = __uint_as_float((unsigned)(r1 >> 32));
        v2f = __uint_as_float((unsigned)(r2 >> 32));
        b0 = lt4[n0_]; b1 = lt4[n1_]; b2 = lt4[n2_];
        a0 = (b0.z - b0.x) * (b0.w - b0.y);
        a1 = (b1.z - b1.x) * (b1.w - b1.y);
        a2 = (b2.z - b2.x) * (b2.w - b2.y);
        if (lane < MAXO - 192) {
            unsigned n3_ = 0xFFFFFFFFu - (unsigned)(r3 & 0xFFFFFFFFull);
            v3f = __uint_as_float((unsigned)(r3 >> 32));
            b3 = lt4[n3_];
            a3 = (b3.z - b3.x) * (b3.w - b3.y);
        } else {
            v3f = 0.f; b3 = make_float4(0.f, 0.f, 0.f, 0.f); a3 = 0.f;
        }
        __syncthreads();   // last cand reads done by all lanes before overwrite
        box4[lane] = b0;        areas[lane] = a0;
        box4[64 + lane] = b1;   areas[64 + lane] = a1;
        box4[128 + lane] = b2;  areas[128 + lane] = a2;
        if (lane < MAXO - 192) {
            box4[192 + lane] = b3;  areas[192 + lane] = a3;
        }
    }
    const bool j3v = (lane < MAXO - 192);
    const u64 vm0 = __ballot(v0f > 0.f);
    const u64 vm1 = __ballot(v1f > 0.f);
    const u64 vm2 = __ballot(v2f > 0.f);
    const u64 vm3 = __ballot(j3v && (v3f > 0.f));
    __syncthreads();   // box4/areas ready; hist no longer needed -> supflat

    u64* supflat = pool;   // NMS phase alias (rows stored only if nonzero)

    // ---- dense suppression matrix: independent row iterations (pipelined),
    //      word-triangular, guard-banded div-free predicate (exact) ----
    u64 nz0 = 0, nz1 = 0, nz2 = 0, nz3 = 0;
    for (int i = 0; i < 64; ++i) {
#pragma clang fp contract(off)
        float4 bi = box4[i]; float ai = areas[i];
        float i0, d0_, i1, d1_, i2, d2_, i3, d3_;
        iou_parts(b0, a0, bi, ai, i0, d0_);
        iou_parts(b1, a1, bi, ai, i1, d1_);
        iou_parts(b2, a2, bi, ai, i2, d2_);
        iou_parts(b3, a3, bi, ai, i3, d3_);
        float t0 = i0 + i0, t1 = i1 + i1, t2 = i2 + i2, t3 = i3 + i3;
        bool su0 = t0 >= d0_, su1 = t1 >= d1_, su2 = t2 >= d2_, su3 = t3 >= d3_;
        bool bd0 = !su0 && (t0 > d0_ * 0.99999952f);
        bool bd1 = !su1 && (t1 > d1_ * 0.99999952f);
        bool bd2 = !su2 && (t2 > d2_ * 0.99999952f);
        bool bd3 = !su3 && (t3 > d3_ * 0.99999952f);
        if (__any(bd0 | bd1 | bd2 | bd3)) {   // ~never
            su0 = bd0 ? (i0 / d0_ >= IOU_TH) : su0;
            su1 = bd1 ? (i1 / d1_ >= IOU_TH) : su1;
            su2 = bd2 ? (i2 / d2_ >= IOU_TH) : su2;
            su3 = bd3 ? (i3 / d3_ >= IOU_TH) : su3;
        }
        u64 s0 = __ballot(su0 && (lane > i));
        u64 s1 = __ballot(su1);
        u64 s2 = __ballot(su2);
        u64 s3 = __ballot(su3 && j3v);
        if ((s0 | s1 | s2 | s3) != 0ull) {
            nz0 |= 1ull << i;
            if (lane == 0) {
                supflat[i * 4 + 0] = s0; supflat[i * 4 + 1] = s1;
                supflat[i * 4 + 2] = s2; supflat[i * 4 + 3] = s3;
            }
        }
    }
    for (int i = 64; i < 128; ++i) {
#pragma clang fp contract(off)
        float4 bi = box4[i]; float ai = areas[i];
        float i1, d1_, i2, d2_, i3, d3_;
        iou_parts(b1, a1, bi, ai, i1, d1_);
        iou_parts(b2, a2, bi, ai, i2, d2_);
        iou_parts(b3, a3, bi, ai, i3, d3_);
        float t1 = i1 + i1, t2 = i2 + i2, t3 = i3 + i3;
        bool su1 = t1 >= d1_, su2 = t2 >= d2_, su3 = t3 >= d3_;
        bool bd1 = !su1 && (t1 > d1_ * 0.99999952f);
        bool bd2 = !su2 && (t2 > d2_ * 0.99999952f);
        bool bd3 = !su3 && (t3 > d3_ * 0.99999952f);
        if (__any(bd1 | bd2 | bd3)) {
            su1 = bd1 ? (i1 / d1_ >= IOU_TH) : su1;
            su2 = bd2 ? (i2 / d2_ >= IOU_TH) : su2;
            su3 = bd3 ? (i3 / d3_ >= IOU_TH) : su3;
        }
        u64 s1 = __ballot(su1 && (64 + lane > i));
        u64 s2 = __ballot(su2);
        u64 s3 = __ballot(su3 && j3v);
        if ((s1 | s2 | s3) != 0ull) {
            nz1 |= 1ull << (i - 64);
            if (lane == 0) {
                supflat[i * 4 + 1] = s1;
                supflat[i * 4 + 2] = s2; supflat[i * 4 + 3] = s3;
            }
        }
    }
    for (int i = 128; i < 192; ++i) {
#pragma clang fp contract(off)
        float4 bi = box4[i]; float ai = areas[i];
        float i2, d2_, i3, d3_;
        iou_parts(b2, a2, bi, ai, i2, d2_);
        iou_parts(b3, a3, bi, ai, i3, d3_);
        float t2 = i2 + i2, t3 = i3 + i3;
        bool su2 = t2 >= d2_, su3 = t3 >= d3_;
        bool bd2 = !su2 && (t2 > d2_ * 0.99999952f);
        bool bd3 = !su3 && (t3 > d3_ * 0.99999952f);
        if (__any(bd2 | bd3)) {
            su2 = bd2 ? (i2 / d2_ >= IOU_TH) : su2;
            su3 = bd3 ? (i3 / d3_ >= IOU_TH) : su3;
        }
        u64 s2 = __ballot(su2 && (128 + lane > i));
        u64 s3 = __ballot(su3 && j3v);
        if ((s2 | s3) != 0ull) {
            nz2 |= 1ull << (i - 128);
            if (lane == 0) {
                supflat[i * 4 + 2] = s2; supflat[i * 4 + 3] = s3;
            }
        }
    }
    for (int i = 192; i < MAXO; ++i) {
#pragma clang fp contract(off)
        float4 bi = box4[i]; float ai = areas[i];
        float i3, d3_;
        iou_parts(b3, a3, bi, ai, i3, d3_);
        float t3 = i3 + i3;
        bool su3 = t3 >= d3_;
        bool bd3 = !su3 && (t3 > d3_ * 0.99999952f);
        if (__any(bd3)) su3 = bd3 ? (i3 / d3_ >= IOU_TH) : su3;
        u64 s3 = __ballot(su3 && j3v && (192 + lane > i));
        if (s3 != 0ull) {
            nz3 |= 1ull << (i - 192);
            if (lane == 0) supflat[i * 4 + 3] = s3;
        }
    }
    __syncthreads();   // supflat visible

    // ---- sparse propagation over nonzero rows (zero rows are no-ops in the
    // reference recurrence). All lanes execute identically.
    u64 k0 = ~0ull, k1 = ~0ull, k2 = ~0ull, k3 = ~0ull;
    {
        int i = -1;
        u64 c;
        if ((c = k0 & vm0 & nz0))      i = __builtin_ctzll(c);
        else if ((c = k1 & vm1 & nz1)) i = 64 + __builtin_ctzll(c);
        else if ((c = k2 & vm2 & nz2)) i = 128 + __builtin_ctzll(c);
        else if ((c = k3 & vm3 & nz3)) i = 192 + __builtin_ctzll(c);
        while (i >= 0) {
            int wr = i >> 6, bit = i & 63;
            if (wr == 0) {
                k0 &= ~supflat[i * 4 + 0]; k1 &= ~supflat[i * 4 + 1];
                k2 &= ~supflat[i * 4 + 2]; k3 &= ~supflat[i * 4 + 3];
            } else if (wr == 1) {
                k1 &= ~supflat[i * 4 + 1];
                k2 &= ~supflat[i * 4 + 2]; k3 &= ~supflat[i * 4 + 3];
            } else if (wr == 2) {
                k2 &= ~supflat[i * 4 + 2]; k3 &= ~supflat[i * 4 + 3];
            } else {
                k3 &= ~supflat[i * 4 + 3];
            }
            u64 above = (bit == 63) ? 0ull : (~0ull << (bit + 1));
            u64 cur = ((wr == 0) ? (k0 & vm0 & nz0)
                     : (wr == 1) ? (k1 & vm1 & nz1)
                     : (wr == 2) ? (k2 & vm2 & nz2)
                                 : (k3 & vm3 & nz3)) & above;
            i = -1;
            while (true) {
                if (cur) { i = wr * 64 + __builtin_ctzll(cur); break; }
                if (++wr >= 4) break;
                cur = (wr == 1) ? (k1 & vm1 & nz1)
                    : (wr == 2) ? (k2 & vm2 & nz2) : (k3 & vm3 & nz3);
            }
        }
    }

    // ---- outputs ----
    {
        float* pv  = pcVals + (size_t)bc * MAXO;
        float4* pb4 = reinterpret_cast<float4*>(pcBoxes + (size_t)bc * MAXO * 4);
        bool kp0 = (k0 >> lane) & 1ull, kp1 = (k1 >> lane) & 1ull;
        bool kp2 = (k2 >> lane) & 1ull, kp3 = (k3 >> lane) & 1ull;
        pv[lane]        = (kp0 && v0f > 0.f) ? v0f : 0.f;
        pv[64 + lane]   = (kp1 && v1f > 0.f) ? v1f : 0.f;
        pv[128 + lane]  = (kp2 && v2f > 0.f) ? v2f : 0.f;
        pb4[lane] = b0; pb4[64 + lane] = b1; pb4[128 + lane] = b2;
        if (j3v) {
            pv[192 + lane] = (kp3 && v3f > 0.f) ? v3f : 0.f;
            pb4[192 + lane] = b3;
        }
    }

    // Compact kept keys into per-image list (ballot-ranked).
    {
        u64 km0 = k0 & vm0, km1 = k1 & vm1, km2 = k2 & vm2, km3 = k3 & vm3;
        int c0 = (int)__popcll(km0), c1 = (int)__popcll(km1);
        int c2 = (int)__popcll(km2), c3 = (int)__popcll(km3);
        int tot = c0 + c1 + c2 + c3;
        int kb = 0;
        if (lane == 0 && tot > 0) kb = atomicAdd(&imgcnt[b], tot);
        kb = __shfl(kb, 0);
        u64 below = (lane == 0) ? 0ull : (~0ull >> (64 - lane));
        u64* dst = imglist + (size_t)b * IMGCAP + kb;
        const u64 himask = 0xFFFFFFFF00000000ull;
        if ((km0 >> lane) & 1ull) {
            unsigned g = (unsigned)((cls - 1) * MAXO + lane);
            dst[__popcll(km0 & below)] =
                (r0 & himask) | (u64)(0xFFFFFFFFu - g);
        }
        if ((km1 >> lane) & 1ull) {
            unsigned g = (unsigned)((cls - 1) * MAXO + 64 + lane);
            dst[c0 + __popcll(km1 & below)] =
                (r1 & himask) | (u64)(0xFFFFFFFFu - g);
        }
        if ((km2 >> lane) & 1ull) {
            unsigned g = (unsigned)((cls - 1) * MAXO + 128 + lane);
            dst[c0 + c1 + __popcll(km2 & below)] =
                (r2 & himask) | (u64)(0xFFFFFFFFu - g);
        }
        if ((km3 >> lane) & 1ull) {
            unsigned g = (unsigned)((cls - 1) * MAXO + 192 + lane);
            dst[c0 + c1 + c2 + __popcll(km3 & below)] =
                (r3 & himask) | (u64)(0xFFFFFFFFu - g);
        }
    }
}

// Kernel 3: per image, exact top-200. Live path reads the compact kept list
// (~15k entries); dense fallback (NZ<200) kept verbatim.
__global__ __launch_bounds__(256) void ssd_final_topk(
    const float* __restrict__ pcVals, const float* __restrict__ pcBoxes,
    const int* __restrict__ imgcnt, const u64* __restrict__ imglist,
    float* __restrict__ out) {
    __shared__ unsigned int hist[NBIN];
    __shared__ u64 cand[CAP];
    __shared__ int wtot[4];
    __shared__ int cnt, cutbin, nztot;

    const int tid  = threadIdx.x;
    const int lane = tid & 63;
    const int wv   = tid >> 6;
    const int b    = blockIdx.x;
    const int TOT  = C1 * MAXO;   // 16000
    const float* pv = pcVals + (size_t)b * TOT;
    const int NZ   = imgcnt[b];

    for (int i = tid; i < NBIN; i += 256) hist[i] = 0u;
    if (tid == 0) { cnt = 0; cutbin = 1; }
    __syncthreads();

    int count;
    if (NZ >= MAXO) {
        const u64* lst = imglist + (size_t)b * IMGCAP;
        for (int i = tid; i < NZ; i += 256) {
            unsigned bits = (unsigned)(lst[i] >> 32);
            unsigned bin = ((bits - BINBASE) >> 15) + 1u;
            if (bin > NBIN - 1) bin = NBIN - 1;
            atomicAdd(&hist[bin], 1u);
        }
        __syncthreads();

        const int base = tid * 8;
        int loc = 0;
        for (int k = 0; k < 8; ++k) loc += (int)hist[base + k];
        int sfx = loc;
        for (int off = 1; off < 64; off <<= 1) {
            int t = __shfl_down(sfx, off, 64);
            if (lane + off < 64) sfx += t;
        }
        if (lane == 0) wtot[wv] = sfx;
        __syncthreads();
        int crossSuf = 0;
        for (int w2 = wv + 1; w2 < 4; ++w2) crossSuf += wtot[w2];
        {
            int S = (sfx - loc) + crossSuf;
            for (int k = 7; k >= 0; --k) {
                int binv = (int)hist[base + k];
                int Sk = S + binv;
                int bin = base + k;
                if (bin >= 1 && Sk >= MAXO && S < MAXO) cutbin = bin;
                S = Sk;
            }
        }
        __syncthreads();
        const int B = cutbin;

        for (int i = tid; i < NZ; i += 256) {
            u64 k = lst[i];
            unsigned bits = (unsigned)(k >> 32);
            unsigned bin = ((bits - BINBASE) >> 15) + 1u;
            if (bin > NBIN - 1) bin = NBIN - 1;
            if ((int)bin >= B) {
                int pos = atomicAdd(&cnt, 1);
                if (pos < CAP) cand[pos] = k;
            }
        }
        __syncthreads();
        count = min(cnt, CAP);
    } else {
        // Dense fallback (dead in practice).
        for (int g = tid; g < TOT; g += 256) {
            float v = pv[g];
            if (v > 0.f) {
                unsigned bits = __float_as_uint(v);
                unsigned bin = ((bits - BINBASE) >> 15) + 1u;
                if (bin > NBIN - 1) bin = NBIN - 1;
                atomicAdd(&hist[bin], 1u);
            }
        }
        __syncthreads();
        const int base = tid * 8;
        int loc = 0;
        for (int k = 0; k < 8; ++k) loc += (int)hist[base + k];
        int sfx = loc;
        for (int off = 1; off < 64; off <<= 1) {
            int t = __shfl_down(sfx, off, 64);
            if (lane + off < 64) sfx += t;
        }
        if (lane == 0) wtot[wv] = sfx;
        __syncthreads();
        int crossSuf = 0;
        for (int w2 = wv + 1; w2 < 4; ++w2) crossSuf += wtot[w2];
        if (tid == 0) nztot = wtot[0] + wtot[1] + wtot[2] + wtot[3];
        {
            int S = (sfx - loc) + crossSuf;
            for (int k = 7; k >= 0; --k) {
                int binv = (int)hist[base + k];
                int Sk = S + binv;
                int bin = base + k;
                if (bin >= 1 && Sk >= MAXO && S < MAXO) cutbin = bin;
                S = Sk;
            }
        }
        __syncthreads();
        int B = (nztot >= MAXO) ? cutbin : 1;

        for (int g = tid; g < TOT; g += 256) {
            float v = pv[g];
            if (v > 0.f) {
                unsigned bits = __float_as_uint(v);
                unsigned bin = ((bits - BINBASE) >> 15) + 1u;
                if (bin > NBIN - 1) bin = NBIN - 1;
                if ((int)bin >= B) {
                    int pos = atomicAdd(&cnt, 1);
                    if (pos < CAP)
                        cand[pos] = ((u64)bits << 32)
                                  | (u64)(0xFFFFFFFFu - (unsigned)g);
                }
            }
        }
        __syncthreads();
        count = min(cnt, CAP);

        if (count < MAXO) {   // zero-fill, smallest flat index first
            if (tid == 0) {
                int c = count;
                for (int g = 0; g < TOT && c < MAXO; ++g) {
                    if (!(pv[g] > 0.f)) {
                        cand[c++] = (u64)(0xFFFFFFFFu - (unsigned)g);
                    }
                }
                cnt = c;
            }
            __syncthreads();
            count = min(cnt, CAP);
        }
    }

    u64 key;
    if (count <= 256) {
        key = (tid < count) ? cand[tid] : 0ull;
        key = regsort256(key, cand, tid);
    } else {
        int P = 256; while (P < count) P <<= 1;
        for (int i = count + tid; i < P; i += 256) cand[i] = 0ull;
        __syncthreads();
        bitonic_desc(cand, P, tid, 256);
        key = cand[tid];
    }

    if (tid < MAXO) {
        float sc      = __uint_as_float((unsigned)(key >> 32));
        unsigned flat = 0xFFFFFFFFu - (unsigned)(key & 0xFFFFFFFFull);
        int cls = (int)(flat / MAXO) + 1;
        const float4 bb =
            reinterpret_cast<const float4*>(pcBoxes)[(size_t)b * TOT + flat];
        reinterpret_cast<float4*>(out)[(size_t)b * MAXO + tid] = bb;
        out[(size_t)BATCH * MAXO * 4 + (size_t)b * MAXO + tid] = (float)cls;
        out[(size_t)BATCH * MAXO * 5 + (size_t)b * MAXO + tid] = sc;
    }
}

extern "C" void kernel_launch(void* const* d_in, const int* in_sizes, int n_in,
                              void* d_out, int out_size, void* d_ws,
                              size_t ws_size, hipStream_t stream) {
    const float* ploc   = (const float*)d_in[0];
    const float* plabel = (const float*)d_in[1];
    const float* dboxes = (const float*)d_in[2];
    float* out = (float*)d_out;

    float* ws      = (float*)d_ws;
    float* ltrb    = ws;                                   // B*N*4
    float* rowmax  = ltrb   + (size_t)BATCH * NANCH * 4;   // B*N
    float* rowsum  = rowmax + (size_t)BATCH * NANCH;       // B*N
    float* pcVals  = rowsum + (size_t)BATCH * NANCH;       // B*80*200
    float* pcBoxes = pcVals + (size_t)BATCH * C1 * MAXO;   // B*80*200*4
    int*   cntg    = (int*)(pcBoxes + (size_t)BATCH * C1 * MAXO * 4);
    int*   imgcnt  = cntg + BATCH * C1;                    // B ints
    char*  after   = (char*)(imgcnt + BATCH);
    u64* bucket = (u64*)(after + ((16 - (((size_t)after) & 15)) & 15));
    u64* imglist = bucket + (size_t)BATCH * C1 * CAPB;     // B * 16000 u64

    hipMemsetAsync(cntg, 0, (size_t)(BATCH * C1 + BATCH) * sizeof(int), stream);
    ssd_decode_stats<<<BATCH * NBLKA, APB, 0, stream>>>(
        ploc, plabel, dboxes, ltrb, rowmax, rowsum, cntg, bucket);
    ssd_class_nms<<<BATCH * C1, 64, 0, stream>>>(
        plabel, rowmax, rowsum, ltrb, cntg, bucket, pcVals, pcBoxes,
        imgcnt, imglist);
    ssd_final_topk<<<BATCH, 256, 0, stream>>>(
        pcVals, pcBoxes, imgcnt, imglist, out);
}

// Round 17
// 193.929 us; speedup vs baseline: 1.5650x; 1.1305x over previous
//
#include <hip/hip_runtime.h>
#include <math.h>

namespace {
constexpr int BATCH = 32;
constexpr int NANCH = 15130;
constexpr int NCLS  = 81;
constexpr int C1    = 80;          // foreground classes
constexpr int MAXO  = 200;
constexpr int APB   = 256;         // anchors per K1 block (= threads)
constexpr int NBLKA = (NANCH + APB - 1) / APB;   // 60
constexpr int CAPK2 = 512;         // K2 cand capacity (live path uses <=256)
constexpr int CAP   = 1024;        // K3 cand capacity
constexpr int CAPB  = 768;         // global bucket capacity (mean 434, sigma 20.5)
constexpr int NBIN  = 2048;        // histogram bins for K3 select
constexpr int NBINK2 = 768;        // K2 bins (shift 16); max used bin 641
constexpr unsigned BINBASE = 0x3D000000u;  // 0.03125f — below any score > 0.05
constexpr int IMGCAP = C1 * MAXO;  // 16000 — worst-case kept per image
}

#define SCORE_TH 0.05f
#define IOU_TH   0.5f

typedef unsigned long long u64;

__device__ __forceinline__ u64 shflx64(u64 v, int mask) {
    int lo = __shfl_xor((int)(unsigned)(v & 0xffffffffull), mask, 64);
    int hi = __shfl_xor((int)(unsigned)(v >> 32), mask, 64);
    return ((u64)(unsigned)hi << 32) | (unsigned)lo;
}

// Descending bitonic sort of P (power of 2) u64 keys in LDS (fallback path).
// Key = (float_bits(score) << 32) | (0xFFFFFFFF - index)
// => order: score desc, then index asc (matches jax.lax.top_k stability).
__device__ __forceinline__ void bitonic_desc(u64* keys, int P,
                                             int tid, int nthr) {
    for (int k = 2; k <= P; k <<= 1) {
        for (int j = k >> 1; j > 0; j >>= 1) {
            for (int i = tid; i < P; i += nthr) {
                int ixj = i ^ j;
                if (ixj > i) {
                    u64 a = keys[i], c = keys[ixj];
                    bool up = ((i & k) == 0);
                    if (up ? (a < c) : (a > c)) { keys[i] = c; keys[ixj] = a; }
                }
            }
            __syncthreads();
        }
    }
}

// Register bitonic sort of 256 keys (one per thread, 256-thread blocks).
// j<64 via shuffles; j in {64,128} via LDS round-trip.
__device__ __forceinline__ u64 regsort256(u64 key, u64* lds, int tid) {
    for (int k = 2; k <= 256; k <<= 1) {
        for (int j = k >> 1; j > 0; j >>= 1) {
            u64 pv;
            if (j < 64) {
                pv = shflx64(key, j);
            } else {
                lds[tid] = key;
                __syncthreads();
                pv = lds[tid ^ j];
            }
            bool up = ((tid & k) == 0);
            bool lt = ((tid & j) == 0);
            u64 mx = (key > pv) ? key : pv;
            u64 mn = (key > pv) ? pv : key;
            key = (up == lt) ? mx : mn;
            if (j >= 64) __syncthreads();
        }
    }
    return key;
}

// Exact intersection/denominator parts of the reference IoU expression.
__device__ __forceinline__ void iou_parts(const float4 bb, const float aa,
                                          const float4 bi, const float ai,
                                          float& in_, float& dn) {
#pragma clang fp contract(off)
    float l = fmaxf(bi.x, bb.x);
    float t = fmaxf(bi.y, bb.y);
    float r = fminf(bi.z, bb.z);
    float d = fminf(bi.w, bb.w);
    in_ = fmaxf(r - l, 0.f) * fmaxf(d - t, 0.f);
    dn  = ai + aa - in_ + 1e-12f;
}

// Kernel 1: one thread per anchor, 81 logits in registers. Threshold via
// guard-banded multiply (exact: band -> IEEE div, wave-uniform __any gate).
__global__ __launch_bounds__(256, 3) void ssd_decode_stats(
    const float* __restrict__ ploc, const float* __restrict__ plabel,
    const float* __restrict__ dboxes,
    float* __restrict__ ltrb, float* __restrict__ rowmax,
    float* __restrict__ rowsum,
    int* __restrict__ cntg, u64* __restrict__ bucket) {
#pragma clang fp contract(off)
    __shared__ int lcnt[C1], lbase[C1], lrank[C1];

    const int tid = threadIdx.x;
    const int b   = blockIdx.x / NBLKA;
    const int n0  = (blockIdx.x % NBLKA) * APB;
    const int n   = n0 + tid;
    const bool act = (n < NANCH);

    if (tid < C1) lcnt[tid] = 0;

    float x[NCLS];
    float s = 1.f;
    u64 w0 = 0, w1 = 0;   // pass bits for classes 1..64, 65..80
    if (act) {
        const float* pl = ploc + (size_t)b * 4 * NANCH + n;
        float px = pl[0], py = pl[NANCH], pw = pl[2 * NANCH],
              ph = pl[3 * NANCH];
        float4 db = reinterpret_cast<const float4*>(dboxes)[n];
        float cx = px * 0.1f * db.z + db.x;
        float cy = py * 0.1f * db.w + db.y;
        float w  = expf(pw * 0.2f) * db.z;
        float h  = expf(ph * 0.2f) * db.w;
        float4 o;
        o.x = cx - 0.5f * w; o.y = cy - 0.5f * h;
        o.z = cx + 0.5f * w; o.w = cy + 0.5f * h;
        reinterpret_cast<float4*>(ltrb)[(size_t)b * NANCH + n] = o;

        const float* pb = plabel + (size_t)b * NCLS * NANCH + n;
#pragma unroll
        for (int c = 0; c < NCLS; ++c) x[c] = pb[(size_t)c * NANCH];

        float m = -INFINITY;
#pragma unroll
        for (int c = 0; c < NCLS; ++c) m = fmaxf(m, x[c]);
#pragma unroll
        for (int c = 0; c < NCLS; ++c) x[c] = expf(x[c] - m);
        s = 0.f;
#pragma unroll
        for (int c = 0; c < NCLS; ++c) s += x[c];   // serial, reference order
        rowmax[(size_t)b * NANCH + n] = m;
        rowsum[(size_t)b * NANCH + n] = s;

        const float sc = s * SCORE_TH;
        const float lo = sc * 0.99999952f;   // (1 - 2^-21)
        const float hi = sc * 1.00000048f;   // (1 + 2^-21)
#pragma unroll
        for (int c = 1; c < NCLS; ++c) {
            float e = x[c];
            bool band = (e >= lo) && (e <= hi);
            bool pass = (e > hi);
            if (__any(band)) pass = band ? ((e / s) > SCORE_TH) : pass;
            if (pass) {
                atomicAdd(&lcnt[c - 1], 1);
                if (c <= 64) w0 |= 1ull << (c - 1);
                else         w1 |= 1ull << (c - 65);
            }
        }
    }
    __syncthreads();

    if (tid < C1) {
        int cn = lcnt[tid];
        lbase[tid] = (cn > 0) ? atomicAdd(&cntg[b * C1 + tid], cn) : 0;
        lrank[tid] = 0;
    }
    __syncthreads();

    if (act) {
#pragma unroll
        for (int c = 1; c < NCLS; ++c) {
            bool pass = (c <= 64) ? ((w0 >> (c - 1)) & 1ull)
                                  : ((w1 >> (c - 65)) & 1ull);
            if (pass) {
                int r = atomicAdd(&lrank[c - 1], 1);
                int pos = lbase[c - 1] + r;
                if (pos < CAPB) {
                    float p = x[c] / s;   // exact IEEE div = reference value
                    bucket[(size_t)(b * C1 + (c - 1)) * CAPB + pos] =
                        ((u64)__float_as_uint(p) << 32)
                        | (u64)(0xFFFFFFFFu - (unsigned)n);
                }
            }
        }
    }
}

// Kernel 2: 4-WAVE cooperative block per (b, class). 256-thread select +
// cooperative sort; suppression matrix striped across waves (rows i = wv
// mod 4, each wave holds the full column set); wave0 propagation/outputs.
__global__ __launch_bounds__(256, 6) void ssd_class_nms(
    const float* __restrict__ plabel, const float* __restrict__ rowmax,
    const float* __restrict__ rowsum, const float* __restrict__ ltrb,
    const int* __restrict__ cntg, const u64* __restrict__ bucket,
    float* __restrict__ pcVals, float* __restrict__ pcBoxes,
    int* __restrict__ imgcnt, u64* __restrict__ imglist) {
    __shared__ u64 pool[MAXO * 4];              // 6.4 KB: hist, then supflat
    __shared__ __align__(16) u64 candbox[CAPK2];// 4 KB: cand, then box4+areas
    __shared__ u64 nzsh[4];
    __shared__ int wtot[4];
    __shared__ int cnt, cutbin, fillcnt;

    unsigned* hist = (unsigned*)pool;           // select-phase alias (3 KB)
    u64* cand = candbox;                        // select/sort/fill alias
    float4* box4 = reinterpret_cast<float4*>(candbox);        // NMS alias
    float* areas = reinterpret_cast<float*>(candbox) + 800;   // bytes 3200..4000

    const int tid  = threadIdx.x;
    const int lane = tid & 63;
    const int wv   = tid >> 6;
    const int b    = blockIdx.x / C1;
    const int cls  = blockIdx.x % C1 + 1;     // skip background
    const int bc   = b * C1 + (cls - 1);

    for (int i = tid; i < NBINK2; i += 256) hist[i] = 0u;
    if (tid == 0) { cnt = 0; cutbin = 1; fillcnt = 0; }
    if (tid < 4) nzsh[tid] = 0ull;
    __syncthreads();

    const float* pl = plabel + ((size_t)b * NCLS + cls) * NANCH;
    const float* rm = rowmax + (size_t)b * NANCH;
    const float* rs = rowsum + (size_t)b * NANCH;
    const u64* bkt = bucket + (size_t)bc * CAPB;

    const int gcount = cntg[bc];
    const bool ovf = (gcount > CAPB);   // uniform; dead in practice
    int gathered;

    if (!ovf) {
        // Pass 1: histogram (bin = ((bits-BINBASE)>>16)+1, monotone in value).
        for (int i = tid; i < gcount; i += 256) {
            unsigned bits = (unsigned)(bkt[i] >> 32);
            unsigned bin = ((bits - BINBASE) >> 16) + 1u;
            if (bin > NBINK2 - 1) bin = NBINK2 - 1;
            atomicAdd(&hist[bin], 1u);
        }
        __syncthreads();

        // Thread owns 3 bins; wave suffix-scan + cross-wave combine.
        const int base = tid * 3;
        int loc = (int)hist[base] + (int)hist[base + 1] + (int)hist[base + 2];
        int sfx = loc;
        for (int off = 1; off < 64; off <<= 1) {
            int t = __shfl_down(sfx, off, 64);
            if (lane + off < 64) sfx += t;
        }
        if (lane == 0) wtot[wv] = sfx;
        __syncthreads();
        int crossSuf = 0;
        for (int w2 = wv + 1; w2 < 4; ++w2) crossSuf += wtot[w2];
        const int nztot = wtot[0] + wtot[1] + wtot[2] + wtot[3];
        {
            int S = (sfx - loc) + crossSuf;
            for (int k = 2; k >= 0; --k) {
                int binv = (int)hist[base + k];
                int Sk = S + binv;
                int bin = base + k;
                if (bin >= 1 && Sk >= MAXO && S < MAXO) cutbin = bin;
                S = Sk;
            }
        }
        __syncthreads();
        const int B = (nztot >= MAXO) ? cutbin : 1;

        // Pass 2: gather keys with bin >= B (top-200 subset; ~205 items).
        for (int i = tid; i < gcount; i += 256) {
            u64 k = bkt[i];
            unsigned bits = (unsigned)(k >> 32);
            unsigned bin = ((bits - BINBASE) >> 16) + 1u;
            if (bin > NBINK2 - 1) bin = NBINK2 - 1;
            if ((int)bin >= B) {
                int pos = atomicAdd(&cnt, 1);
                if (pos < CAPK2) cand[pos] = k;
            }
        }
        __syncthreads();
        gathered = min(cnt, CAPK2);
    } else {
        // Overflow fallback (dead): full rescan, no select.
        for (int n = tid; n < NANCH; n += 256) {
            float p = expf(pl[n] - rm[n]) / rs[n];
            if (p > SCORE_TH) {
                int pos = atomicAdd(&cnt, 1);
                if (pos < CAPK2)
                    cand[pos] = ((u64)__float_as_uint(p) << 32)
                              | (u64)(0xFFFFFFFFu - (unsigned)n);
            }
        }
        __syncthreads();
        gathered = min(cnt, CAPK2);
    }

    // ---- cooperative sort: 1 key/thread; sorted order written to cand ----
    if (gathered <= 256) {
        u64 key = (tid < gathered) ? cand[tid] : 0ull;
        key = regsort256(key, cand, tid);
        __syncthreads();        // regsort's scratch use of cand done
        cand[tid] = key;
        if (tid < CAPK2 - 256) cand[256 + tid] = 0ull;
        __syncthreads();
    } else {
        for (int i = gathered + tid; i < CAPK2; i += 256) cand[i] = 0ull;
        __syncthreads();
        bitonic_desc(cand, CAPK2, tid, 256);
    }

    // <200 positives: fill with smallest anchor idx (top_k zero tie-break). Dead.
    if (gathered < MAXO) {
        int* scanb = (int*)hist;
        const int need = MAXO - gathered;
        for (int base2 = 0; base2 < NANCH; base2 += 256) {
            if (fillcnt >= need) break;   // uniform (LDS, synced)
            int n = base2 + tid;
            int flag = 0;
            if (n < NANCH) {
                float p = expf(pl[n] - rm[n]) / rs[n];
                flag = (p <= SCORE_TH) ? 1 : 0;
            }
            scanb[tid] = flag;
            __syncthreads();
            for (int off = 1; off < 256; off <<= 1) {
                int v  = scanb[tid];
                int vp = (tid >= off) ? scanb[tid - off] : 0;
                __syncthreads();
                scanb[tid] = v + vp;
                __syncthreads();
            }
            int excl = scanb[tid] - flag;
            if (flag && (fillcnt + excl) < need)
                cand[gathered + fillcnt + excl] =
                    (u64)(0xFFFFFFFFu - (unsigned)n);
            __syncthreads();
            if (tid == 0) fillcnt += scanb[255];
            __syncthreads();
        }
        __syncthreads();
    }

    // ---- each wave loads ALL 4 column slots + decodes boxes ----
    u64 r0 = cand[lane], r1 = cand[64 + lane];
    u64 r2 = cand[128 + lane], r3 = cand[192 + lane];
    float4 b0, b1, b2, b3;
    float a0, a1, a2, a3, v0f, v1f, v2f, v3f;
    {
#pragma clang fp contract(off)
        const float4* lt4 = reinterpret_cast<const float4*>(ltrb)
                            + (size_t)b * NANCH;
        unsigned n0_ = 0xFFFFFFFFu - (unsigned)(r0 & 0xFFFFFFFFull);
        unsigned n1_ = 0xFFFFFFFFu - (unsigned)(r1 & 0xFFFFFFFFull);
        unsigned n2_ = 0xFFFFFFFFu - (unsigned)(r2 & 0xFFFFFFFFull);
        v0f = __uint_as_float((unsigned)(r0 >> 32));
        v1f = __uint_as_float((unsigned)(r1 >> 32));
        v2f = __uint_as_float((unsigned)(r2 >> 32));
        b0 = lt4[n0_]; b1 = lt4[n1_]; b2 = lt4[n2_];
        a0 = (b0.z - b0.x) * (b0.w - b0.y);
        a1 = (b1.z - b1.x) * (b1.w - b1.y);
        a2 = (b2.z - b2.x) * (b2.w - b2.y);
        if (lane < MAXO - 192) {
            unsigned n3_ = 0xFFFFFFFFu - (unsigned)(r3 & 0xFFFFFFFFull);
            v3f = __uint_as_float((unsigned)(r3 >> 32));
            b3 = lt4[n3_];
            a3 = (b3.z - b3.x) * (b3.w - b3.y);
        } else {
            v3f = 0.f; b3 = make_float4(0.f, 0.f, 0.f, 0.f); a3 = 0.f;
        }
    }
    __syncthreads();   // all cand reads complete before overwrite
    if (wv == 0) {
        box4[lane] = b0;        areas[lane] = a0;
        box4[64 + lane] = b1;   areas[64 + lane] = a1;
        box4[128 + lane] = b2;  areas[128 + lane] = a2;
        if (lane < MAXO - 192) { box4[192 + lane] = b3; areas[192 + lane] = a3; }
    }
    const bool j3v = (lane < MAXO - 192);
    const u64 vm0 = __ballot(v0f > 0.f);
    const u64 vm1 = __ballot(v1f > 0.f);
    const u64 vm2 = __ballot(v2f > 0.f);
    const u64 vm3 = __ballot(j3v && (v3f > 0.f));
    __syncthreads();   // box4/areas ready; hist dead -> supflat alias

    u64* supflat = pool;

    // ---- suppression matrix, rows striped across waves (i = start+wv, +4),
    //      word-triangular, guard-banded div-free predicate (exact) ----
    u64 nz0 = 0, nz1 = 0, nz2 = 0, nz3 = 0;
    for (int i = wv; i < 64; i += 4) {
#pragma clang fp contract(off)
        float4 bi = box4[i]; float ai = areas[i];
        float i0, d0_, i1, d1_, i2, d2_, i3, d3_;
        iou_parts(b0, a0, bi, ai, i0, d0_);
        iou_parts(b1, a1, bi, ai, i1, d1_);
        iou_parts(b2, a2, bi, ai, i2, d2_);
        iou_parts(b3, a3, bi, ai, i3, d3_);
        float t0 = i0 + i0, t1 = i1 + i1, t2 = i2 + i2, t3 = i3 + i3;
        bool su0 = t0 >= d0_, su1 = t1 >= d1_, su2 = t2 >= d2_, su3 = t3 >= d3_;
        bool bd0 = !su0 && (t0 > d0_ * 0.99999952f);
        bool bd1 = !su1 && (t1 > d1_ * 0.99999952f);
        bool bd2 = !su2 && (t2 > d2_ * 0.99999952f);
        bool bd3 = !su3 && (t3 > d3_ * 0.99999952f);
        if (__any(bd0 | bd1 | bd2 | bd3)) {   // ~never
            su0 = bd0 ? (i0 / d0_ >= IOU_TH) : su0;
            su1 = bd1 ? (i1 / d1_ >= IOU_TH) : su1;
            su2 = bd2 ? (i2 / d2_ >= IOU_TH) : su2;
            su3 = bd3 ? (i3 / d3_ >= IOU_TH) : su3;
        }
        u64 s0 = __ballot(su0 && (lane > i));
        u64 s1 = __ballot(su1);
        u64 s2 = __ballot(su2);
        u64 s3 = __ballot(su3 && j3v);
        if ((s0 | s1 | s2 | s3) != 0ull) {
            nz0 |= 1ull << i;
            if (lane == 0) {
                supflat[i * 4 + 0] = s0; supflat[i * 4 + 1] = s1;
                supflat[i * 4 + 2] = s2; supflat[i * 4 + 3] = s3;
            }
        }
    }
    for (int i = 64 + wv; i < 128; i += 4) {
#pragma clang fp contract(off)
        float4 bi = box4[i]; float ai = areas[i];
        float i1, d1_, i2, d2_, i3, d3_;
        iou_parts(b1, a1, bi, ai, i1, d1_);
        iou_parts(b2, a2, bi, ai, i2, d2_);
        iou_parts(b3, a3, bi, ai, i3, d3_);
        float t1 = i1 + i1, t2 = i2 + i2, t3 = i3 + i3;
        bool su1 = t1 >= d1_, su2 = t2 >= d2_, su3 = t3 >= d3_;
        bool bd1 = !su1 && (t1 > d1_ * 0.99999952f);
        bool bd2 = !su2 && (t2 > d2_ * 0.99999952f);
        bool bd3 = !su3 && (t3 > d3_ * 0.99999952f);
        if (__any(bd1 | bd2 | bd3)) {
            su1 = bd1 ? (i1 / d1_ >= IOU_TH) : su1;
            su2 = bd2 ? (i2 / d2_ >= IOU_TH) : su2;
            su3 = bd3 ? (i3 / d3_ >= IOU_TH) : su3;
        }
        u64 s1 = __ballot(su1 && (64 + lane > i));
        u64 s2 = __ballot(su2);
        u64 s3 = __ballot(su3 && j3v);
        if ((s1 | s2 | s3) != 0ull) {
            nz1 |= 1ull << (i - 64);
            if (lane == 0) {
                supflat[i * 4 + 1] = s1;
                supflat[i * 4 + 2] = s2; supflat[i * 4 + 3] = s3;
            }
        }
    }
    for (int i = 128 + wv; i < 192; i += 4) {
#pragma clang fp contract(off)
        float4 bi = box4[i]; float ai = areas[i];
        float i2, d2_, i3, d3_;
        iou_parts(b2, a2, bi, ai, i2, d2_);
        iou_parts(b3, a3, bi, ai, i3, d3_);
        float t2 = i2 + i2, t3 = i3 + i3;
        bool su2 = t2 >= d2_, su3 = t3 >= d3_;
        bool bd2 = !su2 && (t2 > d2_ * 0.99999952f);
        bool bd3 = !su3 && (t3 > d3_ * 0.99999952f);
        if (__any(bd2 | bd3)) {
            su2 = bd2 ? (i2 / d2_ >= IOU_TH) : su2;
            su3 = bd3 ? (i3 / d3_ >= IOU_TH) : su3;
        }
        u64 s2 = __ballot(su2 && (128 + lane > i));
        u64 s3 = __ballot(su3 && j3v);
        if ((s2 | s3) != 0ull) {
            nz2 |= 1ull << (i - 128);
            if (lane == 0) {
                supflat[i * 4 + 2] = s2; supflat[i * 4 + 3] = s3;
            }
        }
    }
    for (int i = 192 + wv; i < MAXO; i += 4) {
#pragma clang fp contract(off)
        float4 bi = box4[i]; float ai = areas[i];
        float i3, d3_;
        iou_parts(b3, a3, bi, ai, i3, d3_);
        float t3 = i3 + i3;
        bool su3 = t3 >= d3_;
        bool bd3 = !su3 && (t3 > d3_ * 0.99999952f);
        if (__any(bd3)) su3 = bd3 ? (i3 / d3_ >= IOU_TH) : su3;
        u64 s3 = __ballot(su3 && j3v && (192 + lane > i));
        if (s3 != 0ull) {
            nz3 |= 1ull << (i - 192);
            if (lane == 0) supflat[i * 4 + 3] = s3;
        }
    }
    if (lane == 0) {
        if (nz0) atomicOr(&nzsh[0], nz0);
        if (nz1) atomicOr(&nzsh[1], nz1);
        if (nz2) atomicOr(&nzsh[2], nz2);
        if (nz3) atomicOr(&nzsh[3], nz3);
    }
    __syncthreads();   // supflat + nz visible

    if (wv != 0) return;   // no barriers beyond this point

    const u64 znz0 = nzsh[0], znz1 = nzsh[1], znz2 = nzsh[2], znz3 = nzsh[3];

    // ---- sparse propagation over nonzero rows (reference recurrence) ----
    u64 k0 = ~0ull, k1 = ~0ull, k2 = ~0ull, k3 = ~0ull;
    {
        int i = -1;
        u64 c;
        if ((c = k0 & vm0 & znz0))      i = __builtin_ctzll(c);
        else if ((c = k1 & vm1 & znz1)) i = 64 + __builtin_ctzll(c);
        else if ((c = k2 & vm2 & znz2)) i = 128 + __builtin_ctzll(c);
        else if ((c = k3 & vm3 & znz3)) i = 192 + __builtin_ctzll(c);
        while (i >= 0) {
            int wr = i >> 6, bit = i & 63;
            if (wr == 0) {
                k0 &= ~supflat[i * 4 + 0]; k1 &= ~supflat[i * 4 + 1];
                k2 &= ~supflat[i * 4 + 2]; k3 &= ~supflat[i * 4 + 3];
            } else if (wr == 1) {
                k1 &= ~supflat[i * 4 + 1];
                k2 &= ~supflat[i * 4 + 2]; k3 &= ~supflat[i * 4 + 3];
            } else if (wr == 2) {
                k2 &= ~supflat[i * 4 + 2]; k3 &= ~supflat[i * 4 + 3];
            } else {
                k3 &= ~supflat[i * 4 + 3];
            }
            u64 above = (bit == 63) ? 0ull : (~0ull << (bit + 1));
            u64 cur = ((wr == 0) ? (k0 & vm0 & znz0)
                     : (wr == 1) ? (k1 & vm1 & znz1)
                     : (wr == 2) ? (k2 & vm2 & znz2)
                                 : (k3 & vm3 & znz3)) & above;
            i = -1;
            while (true) {
                if (cur) { i = wr * 64 + __builtin_ctzll(cur); break; }
                if (++wr >= 4) break;
                cur = (wr == 1) ? (k1 & vm1 & znz1)
                    : (wr == 2) ? (k2 & vm2 & znz2) : (k3 & vm3 & znz3);
            }
        }
    }

    // ---- outputs (wave 0 holds all slots) ----
    {
        float* pv  = pcVals + (size_t)bc * MAXO;
        float4* pb4 = reinterpret_cast<float4*>(pcBoxes + (size_t)bc * MAXO * 4);
        bool kp0 = (k0 >> lane) & 1ull, kp1 = (k1 >> lane) & 1ull;
        bool kp2 = (k2 >> lane) & 1ull, kp3 = (k3 >> lane) & 1ull;
        pv[lane]        = (kp0 && v0f > 0.f) ? v0f : 0.f;
        pv[64 + lane]   = (kp1 && v1f > 0.f) ? v1f : 0.f;
        pv[128 + lane]  = (kp2 && v2f > 0.f) ? v2f : 0.f;
        pb4[lane] = b0; pb4[64 + lane] = b1; pb4[128 + lane] = b2;
        if (j3v) {
            pv[192 + lane] = (kp3 && v3f > 0.f) ? v3f : 0.f;
            pb4[192 + lane] = b3;
        }
    }

    // Compact kept keys into per-image list (ballot-ranked).
    {
        u64 km0 = k0 & vm0, km1 = k1 & vm1, km2 = k2 & vm2, km3 = k3 & vm3;
        int c0 = (int)__popcll(km0), c1 = (int)__popcll(km1);
        int c2 = (int)__popcll(km2), c3 = (int)__popcll(km3);
        int tot = c0 + c1 + c2 + c3;
        int kb = 0;
        if (lane == 0 && tot > 0) kb = atomicAdd(&imgcnt[b], tot);
        kb = __shfl(kb, 0);
        u64 below = (lane == 0) ? 0ull : (~0ull >> (64 - lane));
        u64* dst = imglist + (size_t)b * IMGCAP + kb;
        const u64 himask = 0xFFFFFFFF00000000ull;
        if ((km0 >> lane) & 1ull) {
            unsigned g = (unsigned)((cls - 1) * MAXO + lane);
            dst[__popcll(km0 & below)] =
                (r0 & himask) | (u64)(0xFFFFFFFFu - g);
        }
        if ((km1 >> lane) & 1ull) {
            unsigned g = (unsigned)((cls - 1) * MAXO + 64 + lane);
            dst[c0 + __popcll(km1 & below)] =
                (r1 & himask) | (u64)(0xFFFFFFFFu - g);
        }
        if ((km2 >> lane) & 1ull) {
            unsigned g = (unsigned)((cls - 1) * MAXO + 128 + lane);
            dst[c0 + c1 + __popcll(km2 & below)] =
                (r2 & himask) | (u64)(0xFFFFFFFFu - g);
        }
        if ((km3 >> lane) & 1ull) {
            unsigned g = (unsigned)((cls - 1) * MAXO + 192 + lane);
            dst[c0 + c1 + c2 + __popcll(km3 & below)] =
                (r3 & himask) | (u64)(0xFFFFFFFFu - g);
        }
    }
}

// Kernel 3: per image, exact top-200. Live path reads the compact kept list;
// dense fallback (NZ<200) kept verbatim.
__global__ __launch_bounds__(256) void ssd_final_topk(
    const float* __restrict__ pcVals, const float* __restrict__ pcBoxes,
    const int* __restrict__ imgcnt, const u64* __restrict__ imglist,
    float* __restrict__ out) {
    __shared__ unsigned int hist[NBIN];
    __shared__ u64 cand[CAP];
    __shared__ int wtot[4];
    __shared__ int cnt, cutbin, nztot;

    const int tid  = threadIdx.x;
    const int lane = tid & 63;
    const int wv   = tid >> 6;
    const int b    = blockIdx.x;
    const int TOT  = C1 * MAXO;   // 16000
    const float* pv = pcVals + (size_t)b * TOT;
    const int NZ   = imgcnt[b];

    for (int i = tid; i < NBIN; i += 256) hist[i] = 0u;
    if (tid == 0) { cnt = 0; cutbin = 1; }
    __syncthreads();

    int count;
    if (NZ >= MAXO) {
        const u64* lst = imglist + (size_t)b * IMGCAP;
        for (int i = tid; i < NZ; i += 256) {
            unsigned bits = (unsigned)(lst[i] >> 32);
            unsigned bin = ((bits - BINBASE) >> 15) + 1u;
            if (bin > NBIN - 1) bin = NBIN - 1;
            atomicAdd(&hist[bin], 1u);
        }
        __syncthreads();

        const int base = tid * 8;
        int loc = 0;
        for (int k = 0; k < 8; ++k) loc += (int)hist[base + k];
        int sfx = loc;
        for (int off = 1; off < 64; off <<= 1) {
            int t = __shfl_down(sfx, off, 64);
            if (lane + off < 64) sfx += t;
        }
        if (lane == 0) wtot[wv] = sfx;
        __syncthreads();
        int crossSuf = 0;
        for (int w2 = wv + 1; w2 < 4; ++w2) crossSuf += wtot[w2];
        {
            int S = (sfx - loc) + crossSuf;
            for (int k = 7; k >= 0; --k) {
                int binv = (int)hist[base + k];
                int Sk = S + binv;
                int bin = base + k;
                if (bin >= 1 && Sk >= MAXO && S < MAXO) cutbin = bin;
                S = Sk;
            }
        }
        __syncthreads();
        const int B = cutbin;

        for (int i = tid; i < NZ; i += 256) {
            u64 k = lst[i];
            unsigned bits = (unsigned)(k >> 32);
            unsigned bin = ((bits - BINBASE) >> 15) + 1u;
            if (bin > NBIN - 1) bin = NBIN - 1;
            if ((int)bin >= B) {
                int pos = atomicAdd(&cnt, 1);
                if (pos < CAP) cand[pos] = k;
            }
        }
        __syncthreads();
        count = min(cnt, CAP);
    } else {
        // Dense fallback (dead in practice).
        for (int g = tid; g < TOT; g += 256) {
            float v = pv[g];
            if (v > 0.f) {
                unsigned bits = __float_as_uint(v);
                unsigned bin = ((bits - BINBASE) >> 15) + 1u;
                if (bin > NBIN - 1) bin = NBIN - 1;
                atomicAdd(&hist[bin], 1u);
            }
        }
        __syncthreads();
        const int base = tid * 8;
        int loc = 0;
        for (int k = 0; k < 8; ++k) loc += (int)hist[base + k];
        int sfx = loc;
        for (int off = 1; off < 64; off <<= 1) {
            int t = __shfl_down(sfx, off, 64);
            if (lane + off < 64) sfx += t;
        }
        if (lane == 0) wtot[wv] = sfx;
        __syncthreads();
        int crossSuf = 0;
        for (int w2 = wv + 1; w2 < 4; ++w2) crossSuf += wtot[w2];
        if (tid == 0) nztot = wtot[0] + wtot[1] + wtot[2] + wtot[3];
        {
            int S = (sfx - loc) + crossSuf;
            for (int k = 7; k >= 0; --k) {
                int binv = (int)hist[base + k];
                int Sk = S + binv;
                int bin = base + k;
                if (bin >= 1 && Sk >= MAXO && S < MAXO) cutbin = bin;
                S = Sk;
            }
        }
        __syncthreads();
        int B = (nztot >= MAXO) ? cutbin : 1;

        for (int g = tid; g < TOT; g += 256) {
            float v = pv[g];
            if (v > 0.f) {
                unsigned bits = __float_as_uint(v);
                unsigned bin = ((bits - BINBASE) >> 15) + 1u;
                if (bin > NBIN - 1) bin = NBIN - 1;
                if ((int)bin >= B) {
                    int pos = atomicAdd(&cnt, 1);
                    if (pos < CAP)
                        cand[pos] = ((u64)bits << 32)
                                  | (u64)(0xFFFFFFFFu - (unsigned)g);
                }
            }
        }
        __syncthreads();
        count = min(cnt, CAP);

        if (count < MAXO) {   // zero-fill, smallest flat index first
            if (tid == 0) {
                int c = count;
                for (int g = 0; g < TOT && c < MAXO; ++g) {
                    if (!(pv[g] > 0.f)) {
                        cand[c++] = (u64)(0xFFFFFFFFu - (unsigned)g);
                    }
                }
                cnt = c;
            }
            __syncthreads();
            count = min(cnt, CAP);
        }
    }

    u64 key;
    if (count <= 256) {
        key = (tid < count) ? cand[tid] : 0ull;
        key = regsort256(key, cand, tid);
    } else {
        int P = 256; while (P < count) P <<= 1;
        for (int i = count + tid; i < P; i += 256) cand[i] = 0ull;
        __syncthreads();
        bitonic_desc(cand, P, tid, 256);
        key = cand[tid];
    }

    if (tid < MAXO) {
        float sc      = __uint_as_float((unsigned)(key >> 32));
        unsigned flat = 0xFFFFFFFFu - (unsigned)(key & 0xFFFFFFFFull);
        int cls = (int)(flat / MAXO) + 1;
        const float4 bb =
            reinterpret_cast<const float4*>(pcBoxes)[(size_t)b * TOT + flat];
        reinterpret_cast<float4*>(out)[(size_t)b * MAXO + tid] = bb;
        out[(size_t)BATCH * MAXO * 4 + (size_t)b * MAXO + tid] = (float)cls;
        out[(size_t)BATCH * MAXO * 5 + (size_t)b * MAXO + tid] = sc;
    }
}

extern "C" void kernel_launch(void* const* d_in, const int* in_sizes, int n_in,
                              void* d_out, int out_size, void* d_ws,
                              size_t ws_size, hipStream_t stream) {
    const float* ploc   = (const float*)d_in[0];
    const float* plabel = (const float*)d_in[1];
    const float* dboxes = (const float*)d_in[2];
    float* out = (float*)d_out;

    float* ws      = (float*)d_ws;
    float* ltrb    = ws;                                   // B*N*4
    float* rowmax  = ltrb   + (size_t)BATCH * NANCH * 4;   // B*N
    float* rowsum  = rowmax + (size_t)BATCH * NANCH;       // B*N
    float* pcVals  = rowsum + (size_t)BATCH * NANCH;       // B*80*200
    float* pcBoxes = pcVals + (size_t)BATCH * C1 * MAXO;   // B*80*200*4
    int*   cntg    = (int*)(pcBoxes + (size_t)BATCH * C1 * MAXO * 4);
    int*   imgcnt  = cntg + BATCH * C1;                    // B ints
    char*  after   = (char*)(imgcnt + BATCH);
    u64* bucket = (u64*)(after + ((16 - (((size_t)after) & 15)) & 15));
    u64* imglist = bucket + (size_t)BATCH * C1 * CAPB;     // B * 16000 u64

    hipMemsetAsync(cntg, 0, (size_t)(BATCH * C1 + BATCH) * sizeof(int), stream);
    ssd_decode_stats<<<BATCH * NBLKA, APB, 0, stream>>>(
        ploc, plabel, dboxes, ltrb, rowmax, rowsum, cntg, bucket);
    ssd_class_nms<<<BATCH * C1, 256, 0, stream>>>(
        plabel, rowmax, rowsum, ltrb, cntg, bucket, pcVals, pcBoxes,
        imgcnt, imglist);
    ssd_final_topk<<<BATCH, 256, 0, stream>>>(
        pcVals, pcBoxes, imgcnt, imglist, out);
}